// Round 15
// baseline (1182.987 us; speedup 1.0000x reference)
//
#include <hip/hip_runtime.h>
#include <hip/hip_cooperative_groups.h>
#include <math.h>

namespace cg = cooperative_groups;

#define NL 10
#define BSZ 2
#define TSEQ 2040
#define TPAD 2048
#define DMOD 256
#define NH 4
#define HDIM 64
#define DFF 1024
#define MPAD (BSZ*TPAD)   // 4096
#define CKV 512           // KV chunk per attention block
#define NCU 256

typedef __attribute__((ext_vector_type(8))) short bf16x8;
typedef __attribute__((ext_vector_type(4))) short bf16x4;
typedef __attribute__((ext_vector_type(4))) float f32x4;

__device__ __forceinline__ ushort f2b(float f){
  union { float f; unsigned u; } v; v.f = f;
  unsigned u = v.u;
  return (ushort)((u + 0x7FFFu + ((u >> 16) & 1u)) >> 16);
}
__device__ __forceinline__ float b2f(ushort h){
  union { unsigned u; float f; } v; v.u = ((unsigned)h) << 16; return v.f;
}

struct GemmSh { ushort A[2][64][72]; ushort B[2][64][72]; float st[64][2][2]; };
struct AttnSh { ushort K[64][72]; ushort V[64][72]; ushort P[4][16][72]; };
union ShU { GemmSh g; AttnSh a; };

// ---- copy sequences -> padded x (zero pad rows) + row stats ----
__global__ __launch_bounds__(256) void copy_in_k(const float* __restrict__ seq, float* __restrict__ x,
                                                 float* __restrict__ pstat){
  int idx = blockIdx.x * 256 + threadIdx.x;
  int row = idx >> 6, c = idx & 63;
  int b = row >> 11, t = row & 2047;
  float4 v = {0.f, 0.f, 0.f, 0.f};
  if (t < TSEQ) v = ((const float4*)(seq + ((size_t)(b * TSEQ + t)) * DMOD))[c];
  ((float4*)(x + (size_t)row * DMOD))[c] = v;
  float s  = v.x + v.y + v.z + v.w;
  float s2 = v.x*v.x + v.y*v.y + v.z*v.z + v.w*v.w;
  #pragma unroll
  for (int off = 1; off < 16; off <<= 1){ s += __shfl_xor(s, off); s2 += __shfl_xor(s2, off); }
  if ((c & 15) == 0){
    float2 pr; pr.x = s; pr.y = s2;
    ((float2*)pstat)[(size_t)row * 4 + (c >> 4)] = pr;
  }
}

// ---- LDS-tiled transpose+cast ----
__global__ __launch_bounds__(256) void wtrans_k(const float* __restrict__ src, ushort* __restrict__ dst,
                                                int N, int K, int NTOT, int row0){
  __shared__ ushort tile[64][72];
  int tid = threadIdx.x;
  int kk0 = blockIdx.x * 64, n0 = blockIdx.y * 64, l = blockIdx.z;
  int kl = tid >> 2, nq = tid & 3;
  const float* sp = src + ((size_t)(l * K + kk0 + kl)) * N + n0 + nq * 16;
  #pragma unroll
  for (int i = 0; i < 4; ++i){
    float4 v = ((const float4*)sp)[i];
    int nb = nq * 16 + i * 4;
    tile[nb + 0][kl] = f2b(v.x);
    tile[nb + 1][kl] = f2b(v.y);
    tile[nb + 2][kl] = f2b(v.z);
    tile[nb + 3][kl] = f2b(v.w);
  }
  __syncthreads();
  int r = tid >> 2, cq = (tid & 3) * 16;
  ushort* dp = dst + ((size_t)(l * NTOT + row0 + n0 + r)) * K + kk0 + cq;
  *(bf16x8*)dp       = *(const bf16x8*)&tile[r][cq];
  *(bf16x8*)(dp + 8) = *(const bf16x8*)&tile[r][cq + 8];
}

// ---- concat qkv biases ----
__global__ __launch_bounds__(256) void bqkv_k(const float* __restrict__ bq, const float* __restrict__ bk,
                                              const float* __restrict__ bv, float* __restrict__ bqkv){
  int idx = blockIdx.x * 256 + threadIdx.x;
  if (idx >= NL * 768) return;
  int l = idx / 768, n = idx % 768;
  float v = (n < 256) ? bq[l * 256 + n] : ((n < 512) ? bk[l * 256 + n - 256] : bv[l * 256 + n - 512]);
  bqkv[idx] = v;
}

// ---- final layernorm -> f32 d_out ----
__global__ __launch_bounds__(256) void lnf_k(const float* __restrict__ x, const float* __restrict__ g,
                                             const float* __restrict__ be, float* __restrict__ outf){
  int tid = threadIdx.x;
  int row = blockIdx.x * 4 + (tid >> 6), lane = tid & 63;
  int b = row / TSEQ, t = row % TSEQ;
  int irow = b * TPAD + t;
  float4 xv = ((const float4*)(x + (size_t)irow * DMOD))[lane];
  float s  = xv.x + xv.y + xv.z + xv.w;
  float s2 = xv.x*xv.x + xv.y*xv.y + xv.z*xv.z + xv.w*xv.w;
  #pragma unroll
  for (int off = 1; off < 64; off <<= 1){ s += __shfl_xor(s, off); s2 += __shfl_xor(s2, off); }
  float mu = s * (1.f/256.f);
  float var = s2 * (1.f/256.f) - mu * mu;
  float rs = rsqrtf(var + 1e-5f);
  float4 gv = ((const float4*)g)[lane];
  float4 bv = ((const float4*)be)[lane];
  float4 ov;
  ov.x = (xv.x - mu) * rs * gv.x + bv.x;
  ov.y = (xv.y - mu) * rs * gv.y + bv.y;
  ov.z = (xv.z - mu) * rs * gv.z + bv.z;
  ov.w = (xv.w - mu) * rs * gv.w + bv.w;
  ((float4*)(outf + (size_t)row * DMOD))[lane] = ov;
}

// ---- device GEMM body: 64x64 tile, BK=128 ----
template<int N, int K, int AMODE, int EPI, int STATS>
__device__ void dev_gemm(int bx, int by, GemmSh& sh,
    const ushort* __restrict__ Ab, const float* __restrict__ Af,
    const float* __restrict__ pstat_in, const float* __restrict__ lng, const float* __restrict__ lnb,
    const ushort* __restrict__ po, const float* __restrict__ pml,
    const ushort* __restrict__ Bt, const float* __restrict__ bias,
    float* __restrict__ xres, float* __restrict__ pstat_out,
    ushort* __restrict__ o0, ushort* __restrict__ o1, ushort* __restrict__ o2){
  int tid = threadIdx.x;
  int w = tid >> 6, lane = tid & 63;
  int wr = w >> 1, wc = w & 1;
  int l15 = lane & 15, l4 = lane >> 4;
  int row0 = bx * 64, col0 = by * 64;
  int r = tid >> 3, c8 = (tid & 7) * 8;

  float muA = 0.f, rsA = 0.f, muB = 0.f, rsB = 0.f;
  if (AMODE == 1){
    const float4* pa = (const float4*)(pstat_in + (size_t)(row0 + r) * 8);
    float4 a0 = pa[0], a1 = pa[1];
    float s = a0.x + a0.z + a1.x + a1.z, q = a0.y + a0.w + a1.y + a1.w;
    muA = s * (1.f/256.f);
    rsA = rsqrtf(q * (1.f/256.f) - muA * muA + 1e-5f);
    const float4* pb = (const float4*)(pstat_in + (size_t)(row0 + r + 32) * 8);
    float4 b0 = pb[0], b1 = pb[1];
    s = b0.x + b0.z + b1.x + b1.z; q = b0.y + b0.w + b1.y + b1.w;
    muB = s * (1.f/256.f);
    rsB = rsqrtf(q * (1.f/256.f) - muB * muB + 1e-5f);
  }

  f32x4 zero = {0.f, 0.f, 0.f, 0.f};
  f32x4 acc[2][2];
  acc[0][0] = zero; acc[0][1] = zero; acc[1][0] = zero; acc[1][1] = zero;

  for (int k0 = 0; k0 < K; k0 += 128){
    #pragma unroll
    for (int ck = 0; ck < 2; ++ck){
      int kk = k0 + ck * 64;
      #pragma unroll
      for (int it = 0; it < 2; ++it){
        int rr = r + it * 32;
        if (AMODE == 0){
          *(bf16x8*)&sh.A[ck][rr][c8] = *(const bf16x8*)(Ab + (size_t)(row0 + rr) * K + kk + c8);
        } else if (AMODE == 1){
          float mu = it ? muB : muA, rs = it ? rsB : rsA;
          const float4* xp = (const float4*)(Af + (size_t)(row0 + rr) * 256 + kk + c8);
          float4 xa = xp[0], xb = xp[1];
          const float4* gp = (const float4*)(lng + kk + c8);
          const float4* bp = (const float4*)(lnb + kk + c8);
          float4 ga = gp[0], gb = gp[1], ba = bp[0], bb = bp[1];
          bf16x8 pk;
          pk[0] = (short)f2b((xa.x - mu) * rs * ga.x + ba.x);
          pk[1] = (short)f2b((xa.y - mu) * rs * ga.y + ba.y);
          pk[2] = (short)f2b((xa.z - mu) * rs * ga.z + ba.z);
          pk[3] = (short)f2b((xa.w - mu) * rs * ga.w + ba.w);
          pk[4] = (short)f2b((xb.x - mu) * rs * gb.x + bb.x);
          pk[5] = (short)f2b((xb.y - mu) * rs * gb.y + bb.y);
          pk[6] = (short)f2b((xb.z - mu) * rs * gb.z + bb.z);
          pk[7] = (short)f2b((xb.w - mu) * rs * gb.w + bb.w);
          *(bf16x8*)&sh.A[ck][rr][c8] = pk;
        } else {
          int m = row0 + rr;
          int t = m & 2047, b_ = m >> 11;
          int qt = t >> 4, r16 = t & 15;
          int hh = kk >> 6;
          int u0 = (((b_ * NH + hh) << 7) + qt) << 2;
          int je = ((qt * 16 + 15) / 17) * 17 + 17; je = je < TSEQ ? je : TSEQ;
          int nch = (je + CKV - 1) >> 9;
          float mm[4]; float mg = -1e30f;
          #pragma unroll
          for (int ch = 0; ch < 4; ++ch){
            mm[ch] = (ch < nch) ? pml[(size_t)(u0 + ch) * 32 + r16 * 2] : -1e30f;
            mg = fmaxf(mg, mm[ch]);
          }
          float aw[4]; float lg = 0.f;
          #pragma unroll
          for (int ch = 0; ch < 4; ++ch){
            float ll = (ch < nch) ? pml[(size_t)(u0 + ch) * 32 + r16 * 2 + 1] : 0.f;
            aw[ch] = (ch < nch) ? __expf(mm[ch] - mg) : 0.f;
            lg += aw[ch] * ll;
          }
          float inv = 1.f / lg;
          float av[8] = {0.f,0.f,0.f,0.f,0.f,0.f,0.f,0.f};
          #pragma unroll
          for (int ch = 0; ch < 4; ++ch){
            bf16x8 pv = *(const bf16x8*)(po + (size_t)(u0 + ch) * 1024 + r16 * 64 + c8);
            #pragma unroll
            for (int j = 0; j < 8; ++j) av[j] += aw[ch] * b2f((ushort)pv[j]);
          }
          bf16x8 pk;
          #pragma unroll
          for (int j = 0; j < 8; ++j) pk[j] = (short)f2b(av[j] * inv);
          *(bf16x8*)&sh.A[ck][rr][c8] = pk;
        }
        *(bf16x8*)&sh.B[ck][rr][c8] = *(const bf16x8*)(Bt + (size_t)(col0 + rr) * K + kk + c8);
      }
    }
    __syncthreads();
    #pragma unroll
    for (int ck = 0; ck < 2; ++ck){
      #pragma unroll
      for (int ks = 0; ks < 2; ++ks){
        bf16x8 af[2], bfr[2];
        #pragma unroll
        for (int i = 0; i < 2; ++i){
          af[i]  = *(const bf16x8*)&sh.A[ck][wr * 32 + i * 16 + l15][ks * 32 + l4 * 8];
          bfr[i] = *(const bf16x8*)&sh.B[ck][wc * 32 + i * 16 + l15][ks * 32 + l4 * 8];
        }
        #pragma unroll
        for (int mr = 0; mr < 2; ++mr)
          #pragma unroll
          for (int nc = 0; nc < 2; ++nc)
            acc[mr][nc] = __builtin_amdgcn_mfma_f32_16x16x32_bf16(af[mr], bfr[nc], acc[mr][nc], 0, 0, 0);
      }
    }
    __syncthreads();
  }

  float sr_[2][4], q2_[2][4];
  if (STATS){
    #pragma unroll
    for (int mr = 0; mr < 2; ++mr)
      #pragma unroll
      for (int rr = 0; rr < 4; ++rr){ sr_[mr][rr] = 0.f; q2_[mr][rr] = 0.f; }
  }
  #pragma unroll
  for (int mr = 0; mr < 2; ++mr){
    #pragma unroll
    for (int nc = 0; nc < 2; ++nc){
      #pragma unroll
      for (int rr = 0; rr < 4; ++rr){
        int m = row0 + wr * 32 + mr * 16 + l4 * 4 + rr;
        int n = col0 + wc * 32 + nc * 16 + l15;
        float v = acc[mr][nc][rr] + bias[n];
        if (EPI == 0){
          int b = m >> 11, t = m & 2047;
          int which = n >> 8, hn = n & 255, hh = hn >> 6, hd = hn & 63;
          if (which == 0)      o0[(((size_t)(b * NH + hh)) * TPAD + t) * HDIM + hd] = f2b(v * 0.125f);
          else if (which == 1) o1[(((size_t)(b * NH + hh)) * TPAD + t) * HDIM + hd] = f2b(v);
          else                 o2[(((size_t)(b * NH + hh)) * HDIM + hd) * TPAD + t] = f2b(v);
        } else if (EPI == 1){
          float xn = xres[(size_t)m * 256 + n] + v;
          xres[(size_t)m * 256 + n] = xn;
          if (STATS){ sr_[mr][rr] += xn; q2_[mr][rr] += xn * xn; }
        } else {
          float uu = 0.7978845608028654f * (v + 0.044715f * v * v * v);
          float e = __expf(2.f * uu);
          float th = 1.f - 2.f / (e + 1.f);
          o0[(size_t)m * N + n] = f2b(0.5f * v * (1.f + th));
        }
      }
    }
  }
  if (STATS){
    #pragma unroll
    for (int mr = 0; mr < 2; ++mr){
      #pragma unroll
      for (int rr = 0; rr < 4; ++rr){
        float s = sr_[mr][rr], q = q2_[mr][rr];
        #pragma unroll
        for (int off = 1; off < 16; off <<= 1){ s += __shfl_xor(s, off); q += __shfl_xor(q, off); }
        if (l15 == 0){
          int rl = wr * 32 + mr * 16 + l4 * 4 + rr;
          sh.st[rl][wc][0] = s;
          sh.st[rl][wc][1] = q;
        }
      }
    }
    __syncthreads();
    if (tid < 64){
      float2 pr;
      pr.x = sh.st[tid][0][0] + sh.st[tid][1][0];
      pr.y = sh.st[tid][0][1] + sh.st[tid][1][1];
      ((float2*)pstat_out)[(size_t)(row0 + tid) * 4 + by] = pr;
    }
    __syncthreads();
  }
}

// ---- device attention body: swapped-operand QK^T, per-lane softmax ----
__device__ void dev_attn(int qg, int ch, int bh, AttnSh& sh,
                         const ushort* __restrict__ qq, const ushort* __restrict__ kkk,
                         const ushort* __restrict__ vt,
                         ushort* __restrict__ po, float* __restrict__ pml){
  int tid = threadIdx.x, w = tid >> 6, lane = tid & 63;
  int l15 = lane & 15, l4 = lane >> 4;
  int r0 = qg * 64;
  int je_blk = ((r0 + 63) / 17 + 1) * 17; je_blk = je_blk < TSEQ ? je_blk : TSEQ;
  int jstart = ch * CKV;
  if (jstart >= je_blk) return;                       // idle (uniform per block)
  int jend = (jstart + CKV) < je_blk ? (jstart + CKV) : je_blk;

  int i0 = r0 + w * 16;
  int je_w = ((i0 + 15) / 17 + 1) * 17; je_w = je_w < TSEQ ? je_w : TSEQ;

  const ushort* qb = qq  + (size_t)bh * TPAD * HDIM;
  const ushort* kb = kkk + (size_t)bh * TPAD * HDIM;
  const ushort* vb = vt  + (size_t)bh * HDIM * TPAD;

  int ig = i0 + l15;
  int ibase = (int)((unsigned)ig / 17u) * 17;
  bf16x8 aq0 = *(const bf16x8*)(qb + (size_t)ig * HDIM + l4 * 8);
  bf16x8 aq1 = *(const bf16x8*)(qb + (size_t)ig * HDIM + 32 + l4 * 8);

  f32x4 zero = {0.f, 0.f, 0.f, 0.f};
  float m_ = -1e30f, l_ = 0.f;
  f32x4 o_[4];
  o_[0] = zero; o_[1] = zero; o_[2] = zero; o_[3] = zero;

  int sr = tid >> 2, sc = (tid & 3) * 16;
  for (int j0 = jstart; j0 < jend; j0 += 64){
    __syncthreads();
    *(bf16x8*)&sh.K[sr][sc]     = *(const bf16x8*)(kb + (size_t)(j0 + sr) * HDIM + sc);
    *(bf16x8*)&sh.K[sr][sc + 8] = *(const bf16x8*)(kb + (size_t)(j0 + sr) * HDIM + sc + 8);
    *(bf16x8*)&sh.V[sr][sc]     = *(const bf16x8*)(vb + (size_t)sr * TPAD + j0 + sc);
    *(bf16x8*)&sh.V[sr][sc + 8] = *(const bf16x8*)(vb + (size_t)sr * TPAD + j0 + sc + 8);
    __syncthreads();
    if (j0 >= je_w) continue;
    f32x4 s[4];
    #pragma unroll
    for (int f = 0; f < 4; ++f){
      bf16x8 kf = *(const bf16x8*)&sh.K[f * 16 + l15][l4 * 8];
      s[f] = __builtin_amdgcn_mfma_f32_16x16x32_bf16(kf, aq0, zero, 0, 0, 0);
    }
    #pragma unroll
    for (int f = 0; f < 4; ++f){
      bf16x8 kf = *(const bf16x8*)&sh.K[f * 16 + l15][32 + l4 * 8];
      s[f] = __builtin_amdgcn_mfma_f32_16x16x32_bf16(kf, aq1, s[f], 0, 0, 0);
    }
    if (j0 + 63 > i0){
      #pragma unroll
      for (int f = 0; f < 4; ++f){
        #pragma unroll
        for (int rr = 0; rr < 4; ++rr){
          int jg = j0 + f * 16 + l4 * 4 + rr;
          bool ok = (jg <= ig) || ((unsigned)(jg - ibase) < 17u);
          s[f][rr] = ok ? s[f][rr] : -1e30f;
        }
      }
    }
    float mf0 = fmaxf(fmaxf(s[0][0], s[0][1]), fmaxf(s[0][2], s[0][3]));
    float mf1 = fmaxf(fmaxf(s[1][0], s[1][1]), fmaxf(s[1][2], s[1][3]));
    float mf2 = fmaxf(fmaxf(s[2][0], s[2][1]), fmaxf(s[2][2], s[2][3]));
    float mf3 = fmaxf(fmaxf(s[3][0], s[3][1]), fmaxf(s[3][2], s[3][3]));
    float mx = fmaxf(fmaxf(mf0, mf1), fmaxf(mf2, mf3));
    mx = fmaxf(mx, __shfl_xor(mx, 16));
    mx = fmaxf(mx, __shfl_xor(mx, 32));
    float mn = fmaxf(m_, mx);
    float alpha = __expf(m_ - mn);
    float ps = 0.f;
    #pragma unroll
    for (int f = 0; f < 4; ++f){
      bf16x4 pk;
      #pragma unroll
      for (int rr = 0; rr < 4; ++rr){
        float p = __expf(s[f][rr] - mn);
        ps += p;
        pk[rr] = (short)f2b(p);
      }
      *(bf16x4*)&sh.P[w][l15][f * 16 + l4 * 4] = pk;
    }
    ps += __shfl_xor(ps, 16);
    ps += __shfl_xor(ps, 32);
    l_ = l_ * alpha + ps;
    m_ = mn;
    #pragma unroll
    for (int f = 0; f < 4; ++f) o_[f] *= alpha;
    #pragma unroll
    for (int ks = 0; ks < 2; ++ks){
      bf16x8 pf = *(const bf16x8*)&sh.P[w][l15][ks * 32 + l4 * 8];
      #pragma unroll
      for (int f = 0; f < 4; ++f){
        bf16x8 vf = *(const bf16x8*)&sh.V[f * 16 + l15][ks * 32 + l4 * 8];
        o_[f] = __builtin_amdgcn_mfma_f32_16x16x32_bf16(vf, pf, o_[f], 0, 0, 0);
      }
    }
  }
  int qt = qg * 4 + w;
  int u = ((bh << 7) + qt) * 4 + ch;
  size_t ob = (size_t)u * 1024;
  #pragma unroll
  for (int f = 0; f < 4; ++f){
    bf16x4 pk;
    #pragma unroll
    for (int rr = 0; rr < 4; ++rr) pk[rr] = (short)f2b(o_[f][rr]);
    *(bf16x4*)&po[ob + (size_t)l15 * 64 + f * 16 + l4 * 4] = pk;
  }
  if (l4 == 0){
    pml[(size_t)u * 32 + l15 * 2 + 0] = m_;
    pml[(size_t)u * 32 + l15 * 2 + 1] = l_;
  }
}

// ---- standalone fallback kernels (same device bodies) ----
template<int N, int K, int AMODE, int EPI, int STATS>
__global__ __launch_bounds__(256) void gemm_k(
    const ushort* Ab, const float* Af, const float* pstat_in, const float* lng, const float* lnb,
    const ushort* po, const float* pml, const ushort* Bt, const float* bias,
    float* xres, float* pstat_out, ushort* o0, ushort* o1, ushort* o2){
  __shared__ GemmSh sh;
  dev_gemm<N,K,AMODE,EPI,STATS>(blockIdx.x, blockIdx.y, sh, Ab, Af, pstat_in, lng, lnb,
                                po, pml, Bt, bias, xres, pstat_out, o0, o1, o2);
}

__global__ __launch_bounds__(256) void attn_tile_k(const ushort* qq, const ushort* kkk, const ushort* vt,
                                                   ushort* po, float* pml){
  __shared__ AttnSh sh;
  dev_attn(blockIdx.x, blockIdx.y, blockIdx.z, sh, qq, kkk, vt, po, pml);
}

// ---- persistent cooperative megakernel: whole layer loop ----
struct MegaP {
  float* x; float* pstatA; float* pstatB;
  ushort *qbuf, *kbuf, *vtbuf, *mid, *po; float* pml;
  const ushort *wqkvT, *wprojT, *w1T, *w2T;
  const float *bqkv, *bproj, *b1, *b2;
  const float *ln1_g, *ln1_b, *ln2_g, *ln2_b;
};

__global__ __launch_bounds__(256) void mega_k(MegaP p){
  __shared__ ShU sh;
  cg::grid_group grid = cg::this_grid();
  for (int l = 0; l < NL; ++l){
    for (int bid = blockIdx.x; bid < 768; bid += gridDim.x)
      dev_gemm<768,256,1,0,0>(bid & 63, bid >> 6, sh.g, nullptr, p.x, p.pstatA,
                              p.ln1_g + l*256, p.ln1_b + l*256, nullptr, nullptr,
                              p.wqkvT + (size_t)l*768*256, p.bqkv + l*768,
                              nullptr, nullptr, p.qbuf, p.kbuf, p.vtbuf);
    grid.sync();
    for (int bid = blockIdx.x; bid < 1024; bid += gridDim.x)
      dev_attn(bid & 31, (bid >> 5) & 3, bid >> 7, sh.a, p.qbuf, p.kbuf, p.vtbuf, p.po, p.pml);
    grid.sync();
    for (int bid = blockIdx.x; bid < 256; bid += gridDim.x)
      dev_gemm<256,256,2,1,1>(bid & 63, bid >> 6, sh.g, nullptr, nullptr, nullptr, nullptr, nullptr,
                              p.po, p.pml, p.wprojT + (size_t)l*256*256, p.bproj + l*256,
                              p.x, p.pstatB, nullptr, nullptr, nullptr);
    grid.sync();
    for (int bid = blockIdx.x; bid < 1024; bid += gridDim.x)
      dev_gemm<1024,256,1,2,0>(bid & 63, bid >> 6, sh.g, nullptr, p.x, p.pstatB,
                               p.ln2_g + l*256, p.ln2_b + l*256, nullptr, nullptr,
                               p.w1T + (size_t)l*1024*256, p.b1 + l*1024,
                               nullptr, nullptr, p.mid, nullptr, nullptr);
    grid.sync();
    for (int bid = blockIdx.x; bid < 256; bid += gridDim.x)
      dev_gemm<256,1024,0,1,1>(bid & 63, bid >> 6, sh.g, p.mid, nullptr, nullptr, nullptr, nullptr,
                               nullptr, nullptr, p.w2T + (size_t)l*256*1024, p.b2 + l*256,
                               p.x, p.pstatA, nullptr, nullptr, nullptr);
    grid.sync();
  }
}

extern "C" void kernel_launch(void* const* d_in, const int* in_sizes, int n_in,
                              void* d_out, int out_size, void* d_ws, size_t ws_size,
                              hipStream_t stream){
  const float* seq    = (const float*)d_in[0];
  const float* ln1_g  = (const float*)d_in[1];
  const float* ln1_b  = (const float*)d_in[2];
  const float* wq     = (const float*)d_in[3];
  const float* bq     = (const float*)d_in[4];
  const float* wk     = (const float*)d_in[5];
  const float* bk     = (const float*)d_in[6];
  const float* wv     = (const float*)d_in[7];
  const float* bv     = (const float*)d_in[8];
  const float* wproj  = (const float*)d_in[9];
  const float* bproj  = (const float*)d_in[10];
  const float* ln2_g  = (const float*)d_in[11];
  const float* ln2_b  = (const float*)d_in[12];
  const float* w1     = (const float*)d_in[13];
  const float* b1     = (const float*)d_in[14];
  const float* w2     = (const float*)d_in[15];
  const float* b2     = (const float*)d_in[16];
  const float* lnf_g  = (const float*)d_in[17];
  const float* lnf_b  = (const float*)d_in[18];

  size_t off = 0;
  char* base = (char*)d_ws;
  auto carve = [&](size_t bytes) -> void* {
    void* p = base + off;
    off += (bytes + 255) & ~(size_t)255;
    return p;
  };
  float*  x      = (float*) carve((size_t)MPAD * DMOD * 4);
  ushort* qbuf   = (ushort*)carve((size_t)BSZ * NH * TPAD * HDIM * 2);
  ushort* kbuf   = (ushort*)carve((size_t)BSZ * NH * TPAD * HDIM * 2);
  ushort* vtbuf  = (ushort*)carve((size_t)BSZ * NH * TPAD * HDIM * 2);
  ushort* mid    = (ushort*)carve((size_t)MPAD * DFF * 2);
  ushort* wqkvT  = (ushort*)carve((size_t)NL * 768 * 256 * 2);
  ushort* wprojT = (ushort*)carve((size_t)NL * 256 * 256 * 2);
  ushort* w1T    = (ushort*)carve((size_t)NL * 1024 * 256 * 2);
  ushort* w2T    = (ushort*)carve((size_t)NL * 256 * 1024 * 2);
  float*  bqkv   = (float*) carve((size_t)NL * 768 * 4);
  ushort* po     = (ushort*)carve((size_t)4096 * 1024 * 2);
  float*  pml    = (float*) carve((size_t)4096 * 32 * 4);
  float*  pstatA = (float*) carve((size_t)MPAD * 8 * 4);
  float*  pstatB = (float*) carve((size_t)MPAD * 8 * 4);
  if (off > ws_size) return;

  // prep
  copy_in_k<<<dim3(MPAD/4), dim3(256), 0, stream>>>(seq, x, pstatA);
  wtrans_k<<<dim3(4, 4, NL),  dim3(256), 0, stream>>>(wq,    wqkvT,  256, 256,  768, 0);
  wtrans_k<<<dim3(4, 4, NL),  dim3(256), 0, stream>>>(wk,    wqkvT,  256, 256,  768, 256);
  wtrans_k<<<dim3(4, 4, NL),  dim3(256), 0, stream>>>(wv,    wqkvT,  256, 256,  768, 512);
  wtrans_k<<<dim3(4, 4, NL),  dim3(256), 0, stream>>>(wproj, wprojT, 256, 256,  256, 0);
  wtrans_k<<<dim3(4, 16, NL), dim3(256), 0, stream>>>(w1,    w1T,   1024, 256, 1024, 0);
  wtrans_k<<<dim3(16, 4, NL), dim3(256), 0, stream>>>(w2,    w2T,    256,1024,  256, 0);
  bqkv_k<<<dim3((NL*768 + 255)/256), dim3(256), 0, stream>>>(bq, bk, bv, bqkv);

  // occupancy-gated cooperative megakernel, with proven multi-dispatch fallback
  int maxb = 0;
  hipError_t qe = hipOccupancyMaxActiveBlocksPerMultiprocessor(&maxb, (const void*)mega_k, 256, 0);
  int nblk = (qe == hipSuccess) ? maxb * NCU : 0;
  if (nblk > 1024) nblk = 1024;

  bool coop_done = false;
  if (nblk >= 256){
    MegaP prm;
    prm.x = x; prm.pstatA = pstatA; prm.pstatB = pstatB;
    prm.qbuf = qbuf; prm.kbuf = kbuf; prm.vtbuf = vtbuf; prm.mid = mid;
    prm.po = po; prm.pml = pml;
    prm.wqkvT = wqkvT; prm.wprojT = wprojT; prm.w1T = w1T; prm.w2T = w2T;
    prm.bqkv = bqkv; prm.bproj = bproj; prm.b1 = b1; prm.b2 = b2;
    prm.ln1_g = ln1_g; prm.ln1_b = ln1_b; prm.ln2_g = ln2_g; prm.ln2_b = ln2_b;
    void* kargs[] = { (void*)&prm };
    hipError_t le = hipLaunchCooperativeKernel((const void*)mega_k, dim3(nblk), dim3(256),
                                               kargs, 0, stream);
    coop_done = (le == hipSuccess);
  }

  if (!coop_done){
    for (int l = 0; l < NL; ++l){
      gemm_k<768,256,1,0,0><<<dim3(64,12), dim3(256), 0, stream>>>(
          nullptr, x, pstatA, ln1_g + l*256, ln1_b + l*256, nullptr, nullptr,
          wqkvT + (size_t)l*768*256, bqkv + l*768, nullptr, nullptr, qbuf, kbuf, vtbuf);
      attn_tile_k<<<dim3(32,4,8), dim3(256), 0, stream>>>(qbuf, kbuf, vtbuf, po, pml);
      gemm_k<256,256,2,1,1><<<dim3(64,4), dim3(256), 0, stream>>>(
          nullptr, nullptr, nullptr, nullptr, nullptr, po, pml,
          wprojT + (size_t)l*256*256, bproj + l*256, x, pstatB, nullptr, nullptr, nullptr);
      gemm_k<1024,256,1,2,0><<<dim3(64,16), dim3(256), 0, stream>>>(
          nullptr, x, pstatB, ln2_g + l*256, ln2_b + l*256, nullptr, nullptr,
          w1T + (size_t)l*1024*256, b1 + l*1024, nullptr, nullptr, mid, nullptr, nullptr);
      gemm_k<256,1024,0,1,1><<<dim3(64,4), dim3(256), 0, stream>>>(
          mid, nullptr, nullptr, nullptr, nullptr, nullptr, nullptr,
          w2T + (size_t)l*256*1024, b2 + l*256, x, pstatA, nullptr, nullptr, nullptr);
    }
  }
  lnf_k<<<dim3(BSZ*TSEQ/4), dim3(256), 0, stream>>>(x, lnf_g, lnf_b, (float*)d_out);
}

// Round 16
// 695.055 us; speedup vs baseline: 1.7020x; 1.7020x over previous
//
#include <hip/hip_runtime.h>
#include <math.h>

#define NL 10
#define BSZ 2
#define TSEQ 2040
#define TPAD 2048
#define DMOD 256
#define NH 4
#define HDIM 64
#define DFF 1024
#define MPAD (BSZ*TPAD)   // 4096
#define CKV 512           // KV chunk per attention block

typedef __attribute__((ext_vector_type(8))) short bf16x8;
typedef __attribute__((ext_vector_type(4))) short bf16x4;
typedef __attribute__((ext_vector_type(4))) float f32x4;

__device__ __forceinline__ ushort f2b(float f){
  union { float f; unsigned u; } v; v.f = f;
  unsigned u = v.u;
  return (ushort)((u + 0x7FFFu + ((u >> 16) & 1u)) >> 16);
}
__device__ __forceinline__ float b2f(ushort h){
  union { unsigned u; float f; } v; v.u = ((unsigned)h) << 16; return v.f;
}
__device__ __forceinline__ void gload16(const ushort* g, ushort* l){
  __builtin_amdgcn_global_load_lds((const __attribute__((address_space(1))) void*)g,
                                   (__attribute__((address_space(3))) void*)l, 16, 0, 0);
}

// ---- copy sequences -> padded x [B][2048][256] f32 (zero pad rows) + row stats ----
__global__ __launch_bounds__(256) void copy_in_k(const float* __restrict__ seq, float* __restrict__ x,
                                                 float* __restrict__ pstat){
  int idx = blockIdx.x * 256 + threadIdx.x;
  int row = idx >> 6, c = idx & 63;
  int b = row >> 11, t = row & 2047;
  float4 v = {0.f, 0.f, 0.f, 0.f};
  if (t < TSEQ) v = ((const float4*)(seq + ((size_t)(b * TSEQ + t)) * DMOD))[c];
  ((float4*)(x + (size_t)row * DMOD))[c] = v;
  float s  = v.x + v.y + v.z + v.w;
  float s2 = v.x*v.x + v.y*v.y + v.z*v.z + v.w*v.w;
  #pragma unroll
  for (int off = 1; off < 16; off <<= 1){ s += __shfl_xor(s, off); s2 += __shfl_xor(s2, off); }
  if ((c & 15) == 0){
    float2 pr; pr.x = s; pr.y = s2;
    ((float2*)pstat)[(size_t)row * 4 + (c >> 4)] = pr;
  }
}

// ---- LDS-tiled transpose+cast: src (L,K,N) f32 -> dst [l][row0+n][k] bf16 ----
__global__ __launch_bounds__(256) void wtrans_k(const float* __restrict__ src, ushort* __restrict__ dst,
                                                int N, int K, int NTOT, int row0){
  __shared__ ushort tile[64][72];
  int tid = threadIdx.x;
  int kk0 = blockIdx.x * 64, n0 = blockIdx.y * 64, l = blockIdx.z;
  int kl = tid >> 2, nq = tid & 3;
  const float* sp = src + ((size_t)(l * K + kk0 + kl)) * N + n0 + nq * 16;
  #pragma unroll
  for (int i = 0; i < 4; ++i){
    float4 v = ((const float4*)sp)[i];
    int nb = nq * 16 + i * 4;
    tile[nb + 0][kl] = f2b(v.x);
    tile[nb + 1][kl] = f2b(v.y);
    tile[nb + 2][kl] = f2b(v.z);
    tile[nb + 3][kl] = f2b(v.w);
  }
  __syncthreads();
  int r = tid >> 2, cq = (tid & 3) * 16;
  ushort* dp = dst + ((size_t)(l * NTOT + row0 + n0 + r)) * K + kk0 + cq;
  *(bf16x8*)dp       = *(const bf16x8*)&tile[r][cq];
  *(bf16x8*)(dp + 8) = *(const bf16x8*)&tile[r][cq + 8];
}

// ---- concat qkv biases ----
__global__ __launch_bounds__(256) void bqkv_k(const float* __restrict__ bq, const float* __restrict__ bk,
                                              const float* __restrict__ bv, float* __restrict__ bqkv){
  int idx = blockIdx.x * 256 + threadIdx.x;
  if (idx >= NL * 768) return;
  int l = idx / 768, n = idx % 768;
  float v = (n < 256) ? bq[l * 256 + n] : ((n < 512) ? bk[l * 256 + n - 256] : bv[l * 256 + n - 512]);
  bqkv[idx] = v;
}

// ---- final layernorm -> f32 d_out (compact rows); 4 rows per block ----
__global__ __launch_bounds__(256) void lnf_k(const float* __restrict__ x, const float* __restrict__ g,
                                             const float* __restrict__ be, float* __restrict__ outf){
  int tid = threadIdx.x;
  int row = blockIdx.x * 4 + (tid >> 6), lane = tid & 63;
  int b = row / TSEQ, t = row % TSEQ;
  int irow = b * TPAD + t;
  float4 xv = ((const float4*)(x + (size_t)irow * DMOD))[lane];
  float s  = xv.x + xv.y + xv.z + xv.w;
  float s2 = xv.x*xv.x + xv.y*xv.y + xv.z*xv.z + xv.w*xv.w;
  #pragma unroll
  for (int off = 1; off < 64; off <<= 1){ s += __shfl_xor(s, off); s2 += __shfl_xor(s2, off); }
  float mu = s * (1.f/256.f);
  float var = s2 * (1.f/256.f) - mu * mu;
  float rs = rsqrtf(var + 1e-5f);
  float4 gv = ((const float4*)g)[lane];
  float4 bv = ((const float4*)be)[lane];
  float4 ov;
  ov.x = (xv.x - mu) * rs * gv.x + bv.x;
  ov.y = (xv.y - mu) * rs * gv.y + bv.y;
  ov.z = (xv.z - mu) * rs * gv.z + bv.z;
  ov.w = (xv.w - mu) * rs * gv.w + bv.w;
  ((float4*)(outf + (size_t)row * DMOD))[lane] = ov;
}

// ---- 64x64-tile GEMM, BK=128; B staged via global_load_lds with XOR-swizzled layout ----
// AMODE 0: A = Ab (bf16 [M][K]); AMODE 1: A = LN(Af) via pstat_in; AMODE 2: A = merged attn
// EPI 0: QKV scatter (q pre-scaled; v [b,h,hd,t]); EPI 1: xres += v; EPI 2: GELU -> o0
// STATS 1: per-(row, colblock) partial {sum,sumsq} of x_new -> pstat_out
template<int N, int K, int AMODE, int EPI, int STATS>
__global__ __launch_bounds__(256) void gemm_k(
    const ushort* __restrict__ Ab, const float* __restrict__ Af,
    const float* __restrict__ pstat_in, const float* __restrict__ lng, const float* __restrict__ lnb,
    const ushort* __restrict__ po, const float* __restrict__ pml,
    const ushort* __restrict__ Bt, const float* __restrict__ bias,
    float* __restrict__ xres, float* __restrict__ pstat_out,
    ushort* __restrict__ o0, ushort* __restrict__ o1, ushort* __restrict__ o2){
  __shared__ ushort Alds[2][64][72];
  __shared__ ushort Blds[2][64][64];     // unpadded; 16B-group XOR swizzle per row
  __shared__ float statLds[STATS ? 64 : 1][2][2];
  int tid = threadIdx.x;
  int w = tid >> 6, lane = tid & 63;
  int wr = w >> 1, wc = w & 1;
  int l15 = lane & 15, l4 = lane >> 4;
  int row0 = blockIdx.x * 64, col0 = blockIdx.y * 64;
  int r = tid >> 3, c8 = (tid & 7) * 8;

  float muA = 0.f, rsA = 0.f, muB = 0.f, rsB = 0.f;
  if (AMODE == 1){
    const float4* pa = (const float4*)(pstat_in + (size_t)(row0 + r) * 8);
    float4 a0 = pa[0], a1 = pa[1];
    float s = a0.x + a0.z + a1.x + a1.z, q = a0.y + a0.w + a1.y + a1.w;
    muA = s * (1.f/256.f);
    rsA = rsqrtf(q * (1.f/256.f) - muA * muA + 1e-5f);
    const float4* pb = (const float4*)(pstat_in + (size_t)(row0 + r + 32) * 8);
    float4 b0 = pb[0], b1 = pb[1];
    s = b0.x + b0.z + b1.x + b1.z; q = b0.y + b0.w + b1.y + b1.w;
    muB = s * (1.f/256.f);
    rsB = rsqrtf(q * (1.f/256.f) - muB * muB + 1e-5f);
  }

  f32x4 zero = {0.f, 0.f, 0.f, 0.f};
  f32x4 acc[2][2];
  acc[0][0] = zero; acc[0][1] = zero; acc[1][0] = zero; acc[1][1] = zero;

  for (int k0 = 0; k0 < K; k0 += 128){
    #pragma unroll
    for (int ck = 0; ck < 2; ++ck){
      int kk = k0 + ck * 64;
      // ---- B via global_load_lds: wave w owns rows [w*16, w*16+16), 2 issues ----
      // LDS slot (row, g') holds original 16B-group g = g' ^ (row&7); source fetches g.
      #pragma unroll
      for (int q = 0; q < 2; ++q){
        int rowl = w * 16 + q * 8 + (lane >> 3);
        int g = (lane & 7) ^ (rowl & 7);
        gload16(Bt + (size_t)(col0 + rowl) * K + kk + g * 8,
                &Blds[ck][w * 16 + q * 8][0]);
      }
      // ---- A staging (reg-staged; padded layout) ----
      #pragma unroll
      for (int it = 0; it < 2; ++it){
        int rr = r + it * 32;
        if (AMODE == 0){
          *(bf16x8*)&Alds[ck][rr][c8] = *(const bf16x8*)(Ab + (size_t)(row0 + rr) * K + kk + c8);
        } else if (AMODE == 1){
          float mu = it ? muB : muA, rs = it ? rsB : rsA;
          const float4* xp = (const float4*)(Af + (size_t)(row0 + rr) * 256 + kk + c8);
          float4 xa = xp[0], xb = xp[1];
          const float4* gp = (const float4*)(lng + kk + c8);
          const float4* bp = (const float4*)(lnb + kk + c8);
          float4 ga = gp[0], gb = gp[1], ba = bp[0], bb = bp[1];
          bf16x8 pk;
          pk[0] = (short)f2b((xa.x - mu) * rs * ga.x + ba.x);
          pk[1] = (short)f2b((xa.y - mu) * rs * ga.y + ba.y);
          pk[2] = (short)f2b((xa.z - mu) * rs * ga.z + ba.z);
          pk[3] = (short)f2b((xa.w - mu) * rs * ga.w + ba.w);
          pk[4] = (short)f2b((xb.x - mu) * rs * gb.x + bb.x);
          pk[5] = (short)f2b((xb.y - mu) * rs * gb.y + bb.y);
          pk[6] = (short)f2b((xb.z - mu) * rs * gb.z + bb.z);
          pk[7] = (short)f2b((xb.w - mu) * rs * gb.w + bb.w);
          *(bf16x8*)&Alds[ck][rr][c8] = pk;
        } else {
          int m = row0 + rr;
          int t = m & 2047, b_ = m >> 11;
          int qt = t >> 4, r16 = t & 15;
          int hh = kk >> 6;
          int u0 = (((b_ * NH + hh) << 7) + qt) << 2;
          int je = ((qt * 16 + 15) / 17) * 17 + 17; je = je < TSEQ ? je : TSEQ;
          int nch = (je + CKV - 1) >> 9;
          float mm[4]; float mg = -1e30f;
          #pragma unroll
          for (int ch = 0; ch < 4; ++ch){
            mm[ch] = (ch < nch) ? pml[(size_t)(u0 + ch) * 32 + r16 * 2] : -1e30f;
            mg = fmaxf(mg, mm[ch]);
          }
          float aw[4]; float lg = 0.f;
          #pragma unroll
          for (int ch = 0; ch < 4; ++ch){
            float ll = (ch < nch) ? pml[(size_t)(u0 + ch) * 32 + r16 * 2 + 1] : 0.f;
            aw[ch] = (ch < nch) ? __expf(mm[ch] - mg) : 0.f;
            lg += aw[ch] * ll;
          }
          float inv = 1.f / lg;
          float av[8] = {0.f,0.f,0.f,0.f,0.f,0.f,0.f,0.f};
          #pragma unroll
          for (int ch = 0; ch < 4; ++ch){
            bf16x8 pv = *(const bf16x8*)(po + (size_t)(u0 + ch) * 1024 + r16 * 64 + c8);
            #pragma unroll
            for (int j = 0; j < 8; ++j) av[j] += aw[ch] * b2f((ushort)pv[j]);
          }
          bf16x8 pk;
          #pragma unroll
          for (int j = 0; j < 8; ++j) pk[j] = (short)f2b(av[j] * inv);
          *(bf16x8*)&Alds[ck][rr][c8] = pk;
        }
      }
    }
    __syncthreads();
    #pragma unroll
    for (int ck = 0; ck < 2; ++ck){
      #pragma unroll
      for (int ks = 0; ks < 2; ++ks){
        bf16x8 af[2], bfr[2];
        #pragma unroll
        for (int i = 0; i < 2; ++i){
          af[i] = *(const bf16x8*)&Alds[ck][wr * 32 + i * 16 + l15][ks * 32 + l4 * 8];
          int rB = wc * 32 + i * 16 + l15;
          int gs = ((ks << 2) | l4) ^ (rB & 7);
          bfr[i] = *(const bf16x8*)&Blds[ck][rB][gs * 8];
        }
        #pragma unroll
        for (int mr = 0; mr < 2; ++mr)
          #pragma unroll
          for (int nc = 0; nc < 2; ++nc)
            acc[mr][nc] = __builtin_amdgcn_mfma_f32_16x16x32_bf16(af[mr], bfr[nc], acc[mr][nc], 0, 0, 0);
      }
    }
    __syncthreads();
  }

  float sr_[2][4], q2_[2][4];
  if (STATS){
    #pragma unroll
    for (int mr = 0; mr < 2; ++mr)
      #pragma unroll
      for (int rr = 0; rr < 4; ++rr){ sr_[mr][rr] = 0.f; q2_[mr][rr] = 0.f; }
  }
  #pragma unroll
  for (int mr = 0; mr < 2; ++mr){
    #pragma unroll
    for (int nc = 0; nc < 2; ++nc){
      #pragma unroll
      for (int rr = 0; rr < 4; ++rr){
        int m = row0 + wr * 32 + mr * 16 + l4 * 4 + rr;
        int n = col0 + wc * 32 + nc * 16 + l15;
        float v = acc[mr][nc][rr] + bias[n];
        if (EPI == 0){
          int b = m >> 11, t = m & 2047;
          int which = n >> 8, hn = n & 255, hh = hn >> 6, hd = hn & 63;
          if (which == 0)      o0[(((size_t)(b * NH + hh)) * TPAD + t) * HDIM + hd] = f2b(v * 0.125f);
          else if (which == 1) o1[(((size_t)(b * NH + hh)) * TPAD + t) * HDIM + hd] = f2b(v);
          else                 o2[(((size_t)(b * NH + hh)) * HDIM + hd) * TPAD + t] = f2b(v);
        } else if (EPI == 1){
          float xn = xres[(size_t)m * 256 + n] + v;
          xres[(size_t)m * 256 + n] = xn;
          if (STATS){ sr_[mr][rr] += xn; q2_[mr][rr] += xn * xn; }
        } else {
          float uu = 0.7978845608028654f * (v + 0.044715f * v * v * v);
          float e = __expf(2.f * uu);
          float th = 1.f - 2.f / (e + 1.f);
          o0[(size_t)m * N + n] = f2b(0.5f * v * (1.f + th));
        }
      }
    }
  }
  if (STATS){
    #pragma unroll
    for (int mr = 0; mr < 2; ++mr){
      #pragma unroll
      for (int rr = 0; rr < 4; ++rr){
        float s = sr_[mr][rr], q = q2_[mr][rr];
        #pragma unroll
        for (int off = 1; off < 16; off <<= 1){ s += __shfl_xor(s, off); q += __shfl_xor(q, off); }
        if (l15 == 0){
          int rl = wr * 32 + mr * 16 + l4 * 4 + rr;
          statLds[rl][wc][0] = s;
          statLds[rl][wc][1] = q;
        }
      }
    }
    __syncthreads();
    if (tid < 64){
      float2 pr;
      pr.x = statLds[tid][0][0] + statLds[tid][1][0];
      pr.y = statLds[tid][0][1] + statLds[tid][1][1];
      ((float2*)pstat_out)[(size_t)(row0 + tid) * 4 + blockIdx.y] = pr;
    }
  }
}

// ---- split-KV flash attention: swapped-operand QK^T, per-lane softmax ----
// block = (qg 64 q-rows, ch 512-KV chunk, bh); grid (32,4,8); 4 waves x 16 q each.
__global__ __launch_bounds__(256) void attn_tile_k(const ushort* __restrict__ qq, const ushort* __restrict__ kkk,
                                                   const ushort* __restrict__ vt,
                                                   ushort* __restrict__ po, float* __restrict__ pml){
  __shared__ ushort Klds[64][72];
  __shared__ ushort Vlds[64][72];
  __shared__ ushort Plds[4][16][72];
  int tid = threadIdx.x, w = tid >> 6, lane = tid & 63;
  int l15 = lane & 15, l4 = lane >> 4;
  int qg = blockIdx.x, ch = blockIdx.y, bh = blockIdx.z;
  int r0 = qg * 64;
  int je_blk = ((r0 + 63) / 17 + 1) * 17; je_blk = je_blk < TSEQ ? je_blk : TSEQ;
  int jstart = ch * CKV;
  if (jstart >= je_blk) return;                       // idle block (uniform)
  int jend = (jstart + CKV) < je_blk ? (jstart + CKV) : je_blk;

  int i0 = r0 + w * 16;
  int je_w = ((i0 + 15) / 17 + 1) * 17; je_w = je_w < TSEQ ? je_w : TSEQ;

  const ushort* qb = qq  + (size_t)bh * TPAD * HDIM;
  const ushort* kb = kkk + (size_t)bh * TPAD * HDIM;
  const ushort* vb = vt  + (size_t)bh * HDIM * TPAD;

  int ig = i0 + l15;
  int ibase = (int)((unsigned)ig / 17u) * 17;
  bf16x8 aq0 = *(const bf16x8*)(qb + (size_t)ig * HDIM + l4 * 8);
  bf16x8 aq1 = *(const bf16x8*)(qb + (size_t)ig * HDIM + 32 + l4 * 8);

  f32x4 zero = {0.f, 0.f, 0.f, 0.f};
  float m_ = -1e30f, l_ = 0.f;
  f32x4 o_[4];
  o_[0] = zero; o_[1] = zero; o_[2] = zero; o_[3] = zero;

  int sr = tid >> 2, sc = (tid & 3) * 16;
  for (int j0 = jstart; j0 < jend; j0 += 64){
    __syncthreads();
    *(bf16x8*)&Klds[sr][sc]     = *(const bf16x8*)(kb + (size_t)(j0 + sr) * HDIM + sc);
    *(bf16x8*)&Klds[sr][sc + 8] = *(const bf16x8*)(kb + (size_t)(j0 + sr) * HDIM + sc + 8);
    *(bf16x8*)&Vlds[sr][sc]     = *(const bf16x8*)(vb + (size_t)sr * TPAD + j0 + sc);
    *(bf16x8*)&Vlds[sr][sc + 8] = *(const bf16x8*)(vb + (size_t)sr * TPAD + j0 + sc + 8);
    __syncthreads();
    if (j0 >= je_w) continue;
    f32x4 s[4];
    #pragma unroll
    for (int f = 0; f < 4; ++f){
      bf16x8 kf = *(const bf16x8*)&Klds[f * 16 + l15][l4 * 8];
      s[f] = __builtin_amdgcn_mfma_f32_16x16x32_bf16(kf, aq0, zero, 0, 0, 0);
    }
    #pragma unroll
    for (int f = 0; f < 4; ++f){
      bf16x8 kf = *(const bf16x8*)&Klds[f * 16 + l15][32 + l4 * 8];
      s[f] = __builtin_amdgcn_mfma_f32_16x16x32_bf16(kf, aq1, s[f], 0, 0, 0);
    }
    if (j0 + 63 > i0){
      #pragma unroll
      for (int f = 0; f < 4; ++f){
        #pragma unroll
        for (int rr = 0; rr < 4; ++rr){
          int jg = j0 + f * 16 + l4 * 4 + rr;
          bool ok = (jg <= ig) || ((unsigned)(jg - ibase) < 17u);
          s[f][rr] = ok ? s[f][rr] : -1e30f;
        }
      }
    }
    float mf0 = fmaxf(fmaxf(s[0][0], s[0][1]), fmaxf(s[0][2], s[0][3]));
    float mf1 = fmaxf(fmaxf(s[1][0], s[1][1]), fmaxf(s[1][2], s[1][3]));
    float mf2 = fmaxf(fmaxf(s[2][0], s[2][1]), fmaxf(s[2][2], s[2][3]));
    float mf3 = fmaxf(fmaxf(s[3][0], s[3][1]), fmaxf(s[3][2], s[3][3]));
    float mx = fmaxf(fmaxf(mf0, mf1), fmaxf(mf2, mf3));
    mx = fmaxf(mx, __shfl_xor(mx, 16));
    mx = fmaxf(mx, __shfl_xor(mx, 32));
    float mn = fmaxf(m_, mx);
    float alpha = __expf(m_ - mn);
    float ps = 0.f;
    #pragma unroll
    for (int f = 0; f < 4; ++f){
      bf16x4 pk;
      #pragma unroll
      for (int rr = 0; rr < 4; ++rr){
        float p = __expf(s[f][rr] - mn);
        ps += p;
        pk[rr] = (short)f2b(p);
      }
      *(bf16x4*)&Plds[w][l15][f * 16 + l4 * 4] = pk;
    }
    ps += __shfl_xor(ps, 16);
    ps += __shfl_xor(ps, 32);
    l_ = l_ * alpha + ps;
    m_ = mn;
    #pragma unroll
    for (int f = 0; f < 4; ++f) o_[f] *= alpha;
    #pragma unroll
    for (int ks = 0; ks < 2; ++ks){
      bf16x8 pf = *(const bf16x8*)&Plds[w][l15][ks * 32 + l4 * 8];
      #pragma unroll
      for (int f = 0; f < 4; ++f){
        bf16x8 vf = *(const bf16x8*)&Vlds[f * 16 + l15][ks * 32 + l4 * 8];
        o_[f] = __builtin_amdgcn_mfma_f32_16x16x32_bf16(vf, pf, o_[f], 0, 0, 0);
      }
    }
  }
  int qt = qg * 4 + w;
  int u = ((bh << 7) + qt) * 4 + ch;
  size_t ob = (size_t)u * 1024;
  #pragma unroll
  for (int f = 0; f < 4; ++f){
    bf16x4 pk;
    #pragma unroll
    for (int rr = 0; rr < 4; ++rr) pk[rr] = (short)f2b(o_[f][rr]);
    *(bf16x4*)&po[ob + (size_t)l15 * 64 + f * 16 + l4 * 4] = pk;
  }
  if (l4 == 0){
    pml[(size_t)u * 32 + l15 * 2 + 0] = m_;
    pml[(size_t)u * 32 + l15 * 2 + 1] = l_;
  }
}

extern "C" void kernel_launch(void* const* d_in, const int* in_sizes, int n_in,
                              void* d_out, int out_size, void* d_ws, size_t ws_size,
                              hipStream_t stream){
  const float* seq    = (const float*)d_in[0];
  const float* ln1_g  = (const float*)d_in[1];
  const float* ln1_b  = (const float*)d_in[2];
  const float* wq     = (const float*)d_in[3];
  const float* bq     = (const float*)d_in[4];
  const float* wk     = (const float*)d_in[5];
  const float* bk     = (const float*)d_in[6];
  const float* wv     = (const float*)d_in[7];
  const float* bv     = (const float*)d_in[8];
  const float* wproj  = (const float*)d_in[9];
  const float* bproj  = (const float*)d_in[10];
  const float* ln2_g  = (const float*)d_in[11];
  const float* ln2_b  = (const float*)d_in[12];
  const float* w1     = (const float*)d_in[13];
  const float* b1     = (const float*)d_in[14];
  const float* w2     = (const float*)d_in[15];
  const float* b2     = (const float*)d_in[16];
  const float* lnf_g  = (const float*)d_in[17];
  const float* lnf_b  = (const float*)d_in[18];

  size_t off = 0;
  char* base = (char*)d_ws;
  auto carve = [&](size_t bytes) -> void* {
    void* p = base + off;
    off += (bytes + 255) & ~(size_t)255;
    return p;
  };
  float*  x      = (float*) carve((size_t)MPAD * DMOD * 4);
  ushort* qbuf   = (ushort*)carve((size_t)BSZ * NH * TPAD * HDIM * 2);
  ushort* kbuf   = (ushort*)carve((size_t)BSZ * NH * TPAD * HDIM * 2);
  ushort* vtbuf  = (ushort*)carve((size_t)BSZ * NH * TPAD * HDIM * 2);
  ushort* mid    = (ushort*)carve((size_t)MPAD * DFF * 2);
  ushort* wqkvT  = (ushort*)carve((size_t)NL * 768 * 256 * 2);
  ushort* wprojT = (ushort*)carve((size_t)NL * 256 * 256 * 2);
  ushort* w1T    = (ushort*)carve((size_t)NL * 1024 * 256 * 2);
  ushort* w2T    = (ushort*)carve((size_t)NL * 256 * 1024 * 2);
  float*  bqkv   = (float*) carve((size_t)NL * 768 * 4);
  ushort* po     = (ushort*)carve((size_t)4096 * 1024 * 2);
  float*  pml    = (float*) carve((size_t)4096 * 32 * 4);
  float*  pstatA = (float*) carve((size_t)MPAD * 8 * 4);
  float*  pstatB = (float*) carve((size_t)MPAD * 8 * 4);
  if (off > ws_size) return;

  // prep
  copy_in_k<<<dim3(MPAD/4), dim3(256), 0, stream>>>(seq, x, pstatA);
  wtrans_k<<<dim3(4, 4, NL),  dim3(256), 0, stream>>>(wq,    wqkvT,  256, 256,  768, 0);
  wtrans_k<<<dim3(4, 4, NL),  dim3(256), 0, stream>>>(wk,    wqkvT,  256, 256,  768, 256);
  wtrans_k<<<dim3(4, 4, NL),  dim3(256), 0, stream>>>(wv,    wqkvT,  256, 256,  768, 512);
  wtrans_k<<<dim3(4, 4, NL),  dim3(256), 0, stream>>>(wproj, wprojT, 256, 256,  256, 0);
  wtrans_k<<<dim3(4, 16, NL), dim3(256), 0, stream>>>(w1,    w1T,   1024, 256, 1024, 0);
  wtrans_k<<<dim3(16, 4, NL), dim3(256), 0, stream>>>(w2,    w2T,    256,1024,  256, 0);
  bqkv_k<<<dim3((NL*768 + 255)/256), dim3(256), 0, stream>>>(bq, bk, bv, bqkv);

  for (int l = 0; l < NL; ++l){
    gemm_k<768,256,1,0,0><<<dim3(64,12), dim3(256), 0, stream>>>(
        nullptr, x, pstatA, ln1_g + l*256, ln1_b + l*256, nullptr, nullptr,
        wqkvT + (size_t)l*768*256, bqkv + l*768, nullptr, nullptr, qbuf, kbuf, vtbuf);
    attn_tile_k<<<dim3(32,4,8), dim3(256), 0, stream>>>(qbuf, kbuf, vtbuf, po, pml);
    gemm_k<256,256,2,1,1><<<dim3(64,4), dim3(256), 0, stream>>>(
        nullptr, nullptr, nullptr, nullptr, nullptr, po, pml,
        wprojT + (size_t)l*256*256, bproj + l*256, x, pstatB, nullptr, nullptr, nullptr);
    gemm_k<1024,256,1,2,0><<<dim3(64,16), dim3(256), 0, stream>>>(
        nullptr, x, pstatB, ln2_g + l*256, ln2_b + l*256, nullptr, nullptr,
        w1T + (size_t)l*1024*256, b1 + l*1024, nullptr, nullptr, mid, nullptr, nullptr);
    gemm_k<256,1024,0,1,1><<<dim3(64,4), dim3(256), 0, stream>>>(
        mid, nullptr, nullptr, nullptr, nullptr, nullptr, nullptr,
        w2T + (size_t)l*256*1024, b2 + l*256, x, pstatA, nullptr, nullptr, nullptr);
  }
  lnf_k<<<dim3(BSZ*TSEQ/4), dim3(256), 0, stream>>>(x, lnf_g, lnf_b, (float*)d_out);
}

// Round 17
// 676.690 us; speedup vs baseline: 1.7482x; 1.0271x over previous
//
#include <hip/hip_runtime.h>
#include <math.h>

#define NL 10
#define BSZ 2
#define TSEQ 2040
#define TPAD 2048
#define DMOD 256
#define NH 4
#define HDIM 64
#define DFF 1024
#define MPAD (BSZ*TPAD)   // 4096
#define CKV 512           // KV chunk per attention block

typedef __attribute__((ext_vector_type(8))) short bf16x8;
typedef __attribute__((ext_vector_type(4))) short bf16x4;
typedef __attribute__((ext_vector_type(4))) float f32x4;

__device__ __forceinline__ ushort f2b(float f){
  union { float f; unsigned u; } v; v.f = f;
  unsigned u = v.u;
  return (ushort)((u + 0x7FFFu + ((u >> 16) & 1u)) >> 16);
}
__device__ __forceinline__ float b2f(ushort h){
  union { unsigned u; float f; } v; v.u = ((unsigned)h) << 16; return v.f;
}

// ---- copy sequences -> padded x [B][2048][256] f32 (zero pad rows) + row stats ----
__global__ __launch_bounds__(256) void copy_in_k(const float* __restrict__ seq, float* __restrict__ x,
                                                 float* __restrict__ pstat){
  int idx = blockIdx.x * 256 + threadIdx.x;
  int row = idx >> 6, c = idx & 63;
  int b = row >> 11, t = row & 2047;
  float4 v = {0.f, 0.f, 0.f, 0.f};
  if (t < TSEQ) v = ((const float4*)(seq + ((size_t)(b * TSEQ + t)) * DMOD))[c];
  ((float4*)(x + (size_t)row * DMOD))[c] = v;
  float s  = v.x + v.y + v.z + v.w;
  float s2 = v.x*v.x + v.y*v.y + v.z*v.z + v.w*v.w;
  #pragma unroll
  for (int off = 1; off < 16; off <<= 1){ s += __shfl_xor(s, off); s2 += __shfl_xor(s2, off); }
  if ((c & 15) == 0){
    float2 pr; pr.x = s; pr.y = s2;
    ((float2*)pstat)[(size_t)row * 4 + (c >> 4)] = pr;
  }
}

// ---- LDS-tiled transpose+cast: src (L,K,N) f32 -> dst [l][row0+n][k] bf16 ----
__global__ __launch_bounds__(256) void wtrans_k(const float* __restrict__ src, ushort* __restrict__ dst,
                                                int N, int K, int NTOT, int row0){
  __shared__ ushort tile[64][72];
  int tid = threadIdx.x;
  int kk0 = blockIdx.x * 64, n0 = blockIdx.y * 64, l = blockIdx.z;
  int kl = tid >> 2, nq = tid & 3;
  const float* sp = src + ((size_t)(l * K + kk0 + kl)) * N + n0 + nq * 16;
  #pragma unroll
  for (int i = 0; i < 4; ++i){
    float4 v = ((const float4*)sp)[i];
    int nb = nq * 16 + i * 4;
    tile[nb + 0][kl] = f2b(v.x);
    tile[nb + 1][kl] = f2b(v.y);
    tile[nb + 2][kl] = f2b(v.z);
    tile[nb + 3][kl] = f2b(v.w);
  }
  __syncthreads();
  int r = tid >> 2, cq = (tid & 3) * 16;
  ushort* dp = dst + ((size_t)(l * NTOT + row0 + n0 + r)) * K + kk0 + cq;
  *(bf16x8*)dp       = *(const bf16x8*)&tile[r][cq];
  *(bf16x8*)(dp + 8) = *(const bf16x8*)&tile[r][cq + 8];
}

// ---- concat qkv biases ----
__global__ __launch_bounds__(256) void bqkv_k(const float* __restrict__ bq, const float* __restrict__ bk,
                                              const float* __restrict__ bv, float* __restrict__ bqkv){
  int idx = blockIdx.x * 256 + threadIdx.x;
  if (idx >= NL * 768) return;
  int l = idx / 768, n = idx % 768;
  float v = (n < 256) ? bq[l * 256 + n] : ((n < 512) ? bk[l * 256 + n - 256] : bv[l * 256 + n - 512]);
  bqkv[idx] = v;
}

// ---- final layernorm -> f32 d_out (compact rows); 4 rows per block ----
__global__ __launch_bounds__(256) void lnf_k(const float* __restrict__ x, const float* __restrict__ g,
                                             const float* __restrict__ be, float* __restrict__ outf){
  int tid = threadIdx.x;
  int row = blockIdx.x * 4 + (tid >> 6), lane = tid & 63;
  int b = row / TSEQ, t = row % TSEQ;
  int irow = b * TPAD + t;
  float4 xv = ((const float4*)(x + (size_t)irow * DMOD))[lane];
  float s  = xv.x + xv.y + xv.z + xv.w;
  float s2 = xv.x*xv.x + xv.y*xv.y + xv.z*xv.z + xv.w*xv.w;
  #pragma unroll
  for (int off = 1; off < 64; off <<= 1){ s += __shfl_xor(s, off); s2 += __shfl_xor(s2, off); }
  float mu = s * (1.f/256.f);
  float var = s2 * (1.f/256.f) - mu * mu;
  float rs = rsqrtf(var + 1e-5f);
  float4 gv = ((const float4*)g)[lane];
  float4 bv = ((const float4*)be)[lane];
  float4 ov;
  ov.x = (xv.x - mu) * rs * gv.x + bv.x;
  ov.y = (xv.y - mu) * rs * gv.y + bv.y;
  ov.z = (xv.z - mu) * rs * gv.z + bv.z;
  ov.w = (xv.w - mu) * rs * gv.w + bv.w;
  ((float4*)(outf + (size_t)row * DMOD))[lane] = ov;
}

// ---- 64x64-tile GEMM, BK=128 (two K-chunks per barrier pair) ----
// AMODE 0: A = Ab (bf16 [M][K]); AMODE 1: A = LN(Af) via pstat_in; AMODE 2: A = merged attn
// EPI 0: QKV scatter (q pre-scaled; v [b,h,hd,t]); EPI 1: xres += v; EPI 2: GELU -> o0
// STATS 1: per-(row, colblock) partial {sum,sumsq} of x_new -> pstat_out
template<int N, int K, int AMODE, int EPI, int STATS>
__global__ __launch_bounds__(256) void gemm_k(
    const ushort* __restrict__ Ab, const float* __restrict__ Af,
    const float* __restrict__ pstat_in, const float* __restrict__ lng, const float* __restrict__ lnb,
    const ushort* __restrict__ po, const float* __restrict__ pml,
    const ushort* __restrict__ Bt, const float* __restrict__ bias,
    float* __restrict__ xres, float* __restrict__ pstat_out,
    ushort* __restrict__ o0, ushort* __restrict__ o1, ushort* __restrict__ o2){
  __shared__ ushort Alds[2][64][72];
  __shared__ ushort Blds[2][64][72];
  __shared__ float statLds[STATS ? 64 : 1][2][2];
  int tid = threadIdx.x;
  int w = tid >> 6, lane = tid & 63;
  int wr = w >> 1, wc = w & 1;
  int l15 = lane & 15, l4 = lane >> 4;
  int row0 = blockIdx.x * 64, col0 = blockIdx.y * 64;
  int r = tid >> 3, c8 = (tid & 7) * 8;

  float muA = 0.f, rsA = 0.f, muB = 0.f, rsB = 0.f;
  if (AMODE == 1){
    const float4* pa = (const float4*)(pstat_in + (size_t)(row0 + r) * 8);
    float4 a0 = pa[0], a1 = pa[1];
    float s = a0.x + a0.z + a1.x + a1.z, q = a0.y + a0.w + a1.y + a1.w;
    muA = s * (1.f/256.f);
    rsA = rsqrtf(q * (1.f/256.f) - muA * muA + 1e-5f);
    const float4* pb = (const float4*)(pstat_in + (size_t)(row0 + r + 32) * 8);
    float4 b0 = pb[0], b1 = pb[1];
    s = b0.x + b0.z + b1.x + b1.z; q = b0.y + b0.w + b1.y + b1.w;
    muB = s * (1.f/256.f);
    rsB = rsqrtf(q * (1.f/256.f) - muB * muB + 1e-5f);
  }

  f32x4 zero = {0.f, 0.f, 0.f, 0.f};
  f32x4 acc[2][2];
  acc[0][0] = zero; acc[0][1] = zero; acc[1][0] = zero; acc[1][1] = zero;

  for (int k0 = 0; k0 < K; k0 += 128){
    #pragma unroll
    for (int ck = 0; ck < 2; ++ck){
      int kk = k0 + ck * 64;
      #pragma unroll
      for (int it = 0; it < 2; ++it){
        int rr = r + it * 32;
        if (AMODE == 0){
          *(bf16x8*)&Alds[ck][rr][c8] = *(const bf16x8*)(Ab + (size_t)(row0 + rr) * K + kk + c8);
        } else if (AMODE == 1){
          float mu = it ? muB : muA, rs = it ? rsB : rsA;
          const float4* xp = (const float4*)(Af + (size_t)(row0 + rr) * 256 + kk + c8);
          float4 xa = xp[0], xb = xp[1];
          const float4* gp = (const float4*)(lng + kk + c8);
          const float4* bp = (const float4*)(lnb + kk + c8);
          float4 ga = gp[0], gb = gp[1], ba = bp[0], bb = bp[1];
          bf16x8 pk;
          pk[0] = (short)f2b((xa.x - mu) * rs * ga.x + ba.x);
          pk[1] = (short)f2b((xa.y - mu) * rs * ga.y + ba.y);
          pk[2] = (short)f2b((xa.z - mu) * rs * ga.z + ba.z);
          pk[3] = (short)f2b((xa.w - mu) * rs * ga.w + ba.w);
          pk[4] = (short)f2b((xb.x - mu) * rs * gb.x + bb.x);
          pk[5] = (short)f2b((xb.y - mu) * rs * gb.y + bb.y);
          pk[6] = (short)f2b((xb.z - mu) * rs * gb.z + bb.z);
          pk[7] = (short)f2b((xb.w - mu) * rs * gb.w + bb.w);
          *(bf16x8*)&Alds[ck][rr][c8] = pk;
        } else {
          int m = row0 + rr;
          int t = m & 2047, b_ = m >> 11;
          int qt = t >> 4, r16 = t & 15;
          int hh = kk >> 6;
          int u0 = (((b_ * NH + hh) << 7) + qt) << 2;
          int je = ((qt * 16 + 15) / 17) * 17 + 17; je = je < TSEQ ? je : TSEQ;
          int nch = (je + CKV - 1) >> 9;
          float mm[4]; float mg = -1e30f;
          #pragma unroll
          for (int ch = 0; ch < 4; ++ch){
            mm[ch] = (ch < nch) ? pml[(size_t)(u0 + ch) * 32 + r16 * 2] : -1e30f;
            mg = fmaxf(mg, mm[ch]);
          }
          float aw[4]; float lg = 0.f;
          #pragma unroll
          for (int ch = 0; ch < 4; ++ch){
            float ll = (ch < nch) ? pml[(size_t)(u0 + ch) * 32 + r16 * 2 + 1] : 0.f;
            aw[ch] = (ch < nch) ? __expf(mm[ch] - mg) : 0.f;
            lg += aw[ch] * ll;
          }
          float inv = 1.f / lg;
          float av[8] = {0.f,0.f,0.f,0.f,0.f,0.f,0.f,0.f};
          #pragma unroll
          for (int ch = 0; ch < 4; ++ch){
            bf16x8 pv = *(const bf16x8*)(po + (size_t)(u0 + ch) * 1024 + r16 * 64 + c8);
            #pragma unroll
            for (int j = 0; j < 8; ++j) av[j] += aw[ch] * b2f((ushort)pv[j]);
          }
          bf16x8 pk;
          #pragma unroll
          for (int j = 0; j < 8; ++j) pk[j] = (short)f2b(av[j] * inv);
          *(bf16x8*)&Alds[ck][rr][c8] = pk;
        }
        *(bf16x8*)&Blds[ck][rr][c8] = *(const bf16x8*)(Bt + (size_t)(col0 + rr) * K + kk + c8);
      }
    }
    __syncthreads();
    #pragma unroll
    for (int ck = 0; ck < 2; ++ck){
      #pragma unroll
      for (int ks = 0; ks < 2; ++ks){
        bf16x8 af[2], bfr[2];
        #pragma unroll
        for (int i = 0; i < 2; ++i){
          af[i]  = *(const bf16x8*)&Alds[ck][wr * 32 + i * 16 + l15][ks * 32 + l4 * 8];
          bfr[i] = *(const bf16x8*)&Blds[ck][wc * 32 + i * 16 + l15][ks * 32 + l4 * 8];
        }
        #pragma unroll
        for (int mr = 0; mr < 2; ++mr)
          #pragma unroll
          for (int nc = 0; nc < 2; ++nc)
            acc[mr][nc] = __builtin_amdgcn_mfma_f32_16x16x32_bf16(af[mr], bfr[nc], acc[mr][nc], 0, 0, 0);
      }
    }
    __syncthreads();
  }

  float sr_[2][4], q2_[2][4];
  if (STATS){
    #pragma unroll
    for (int mr = 0; mr < 2; ++mr)
      #pragma unroll
      for (int rr = 0; rr < 4; ++rr){ sr_[mr][rr] = 0.f; q2_[mr][rr] = 0.f; }
  }
  #pragma unroll
  for (int mr = 0; mr < 2; ++mr){
    #pragma unroll
    for (int nc = 0; nc < 2; ++nc){
      #pragma unroll
      for (int rr = 0; rr < 4; ++rr){
        int m = row0 + wr * 32 + mr * 16 + l4 * 4 + rr;
        int n = col0 + wc * 32 + nc * 16 + l15;
        float v = acc[mr][nc][rr] + bias[n];
        if (EPI == 0){
          int b = m >> 11, t = m & 2047;
          int which = n >> 8, hn = n & 255, hh = hn >> 6, hd = hn & 63;
          if (which == 0)      o0[(((size_t)(b * NH + hh)) * TPAD + t) * HDIM + hd] = f2b(v * 0.125f);
          else if (which == 1) o1[(((size_t)(b * NH + hh)) * TPAD + t) * HDIM + hd] = f2b(v);
          else                 o2[(((size_t)(b * NH + hh)) * HDIM + hd) * TPAD + t] = f2b(v);
        } else if (EPI == 1){
          float xn = xres[(size_t)m * 256 + n] + v;
          xres[(size_t)m * 256 + n] = xn;
          if (STATS){ sr_[mr][rr] += xn; q2_[mr][rr] += xn * xn; }
        } else {
          float uu = 0.7978845608028654f * (v + 0.044715f * v * v * v);
          float e = __expf(2.f * uu);
          float th = 1.f - 2.f / (e + 1.f);
          o0[(size_t)m * N + n] = f2b(0.5f * v * (1.f + th));
        }
      }
    }
  }
  if (STATS){
    #pragma unroll
    for (int mr = 0; mr < 2; ++mr){
      #pragma unroll
      for (int rr = 0; rr < 4; ++rr){
        float s = sr_[mr][rr], q = q2_[mr][rr];
        #pragma unroll
        for (int off = 1; off < 16; off <<= 1){ s += __shfl_xor(s, off); q += __shfl_xor(q, off); }
        if (l15 == 0){
          int rl = wr * 32 + mr * 16 + l4 * 4 + rr;
          statLds[rl][wc][0] = s;
          statLds[rl][wc][1] = q;
        }
      }
    }
    __syncthreads();
    if (tid < 64){
      float2 pr;
      pr.x = statLds[tid][0][0] + statLds[tid][1][0];
      pr.y = statLds[tid][0][1] + statLds[tid][1][1];
      ((float2*)pstat_out)[(size_t)(row0 + tid) * 4 + blockIdx.y] = pr;
    }
  }
}

// ---- split-KV flash attention: swapped-operand QK^T, per-lane softmax,
//      defer-max rescale (T13) + setprio around MFMA clusters (T5) ----
// block = (qg 64 q-rows, ch 512-KV chunk, bh); grid (32,4,8); 4 waves x 16 q each.
__global__ __launch_bounds__(256) void attn_tile_k(const ushort* __restrict__ qq, const ushort* __restrict__ kkk,
                                                   const ushort* __restrict__ vt,
                                                   ushort* __restrict__ po, float* __restrict__ pml){
  __shared__ ushort Klds[64][72];
  __shared__ ushort Vlds[64][72];
  __shared__ ushort Plds[4][16][72];
  int tid = threadIdx.x, w = tid >> 6, lane = tid & 63;
  int l15 = lane & 15, l4 = lane >> 4;
  int qg = blockIdx.x, ch = blockIdx.y, bh = blockIdx.z;
  int r0 = qg * 64;
  int je_blk = ((r0 + 63) / 17 + 1) * 17; je_blk = je_blk < TSEQ ? je_blk : TSEQ;
  int jstart = ch * CKV;
  if (jstart >= je_blk) return;                       // idle block (uniform)
  int jend = (jstart + CKV) < je_blk ? (jstart + CKV) : je_blk;

  int i0 = r0 + w * 16;
  int je_w = ((i0 + 15) / 17 + 1) * 17; je_w = je_w < TSEQ ? je_w : TSEQ;

  const ushort* qb = qq  + (size_t)bh * TPAD * HDIM;
  const ushort* kb = kkk + (size_t)bh * TPAD * HDIM;
  const ushort* vb = vt  + (size_t)bh * HDIM * TPAD;

  int ig = i0 + l15;                                  // this lane's query row
  int ibase = (int)((unsigned)ig / 17u) * 17;         // its block start
  bf16x8 aq0 = *(const bf16x8*)(qb + (size_t)ig * HDIM + l4 * 8);
  bf16x8 aq1 = *(const bf16x8*)(qb + (size_t)ig * HDIM + 32 + l4 * 8);

  f32x4 zero = {0.f, 0.f, 0.f, 0.f};
  float m_ = -1e30f, l_ = 0.f;
  f32x4 o_[4];
  o_[0] = zero; o_[1] = zero; o_[2] = zero; o_[3] = zero;

  int sr = tid >> 2, sc = (tid & 3) * 16;             // staging: 4 threads/row, 32B each
  for (int j0 = jstart; j0 < jend; j0 += 64){
    __syncthreads();
    *(bf16x8*)&Klds[sr][sc]     = *(const bf16x8*)(kb + (size_t)(j0 + sr) * HDIM + sc);
    *(bf16x8*)&Klds[sr][sc + 8] = *(const bf16x8*)(kb + (size_t)(j0 + sr) * HDIM + sc + 8);
    *(bf16x8*)&Vlds[sr][sc]     = *(const bf16x8*)(vb + (size_t)sr * TPAD + j0 + sc);
    *(bf16x8*)&Vlds[sr][sc + 8] = *(const bf16x8*)(vb + (size_t)sr * TPAD + j0 + sc + 8);
    __syncthreads();
    if (j0 >= je_w) continue;
    f32x4 s[4];
    __builtin_amdgcn_s_setprio(1);
    #pragma unroll
    for (int f = 0; f < 4; ++f){
      bf16x8 kf = *(const bf16x8*)&Klds[f * 16 + l15][l4 * 8];
      s[f] = __builtin_amdgcn_mfma_f32_16x16x32_bf16(kf, aq0, zero, 0, 0, 0);
    }
    #pragma unroll
    for (int f = 0; f < 4; ++f){
      bf16x8 kf = *(const bf16x8*)&Klds[f * 16 + l15][32 + l4 * 8];
      s[f] = __builtin_amdgcn_mfma_f32_16x16x32_bf16(kf, aq1, s[f], 0, 0, 0);
    }
    __builtin_amdgcn_s_setprio(0);
    if (j0 + 63 > i0){
      #pragma unroll
      for (int f = 0; f < 4; ++f){
        #pragma unroll
        for (int rr = 0; rr < 4; ++rr){
          int jg = j0 + f * 16 + l4 * 4 + rr;
          bool ok = (jg <= ig) || ((unsigned)(jg - ibase) < 17u);
          s[f][rr] = ok ? s[f][rr] : -1e30f;
        }
      }
    }
    float mf0 = fmaxf(fmaxf(s[0][0], s[0][1]), fmaxf(s[0][2], s[0][3]));
    float mf1 = fmaxf(fmaxf(s[1][0], s[1][1]), fmaxf(s[1][2], s[1][3]));
    float mf2 = fmaxf(fmaxf(s[2][0], s[2][1]), fmaxf(s[2][2], s[2][3]));
    float mf3 = fmaxf(fmaxf(s[3][0], s[3][1]), fmaxf(s[3][2], s[3][3]));
    float mx = fmaxf(fmaxf(mf0, mf1), fmaxf(mf2, mf3));
    mx = fmaxf(mx, __shfl_xor(mx, 16));
    mx = fmaxf(mx, __shfl_xor(mx, 32));
    // defer-max: skip O/l rescale when max growth is bounded (P <= e^8, bf16-safe)
    float mn = m_;
    if (!__all(mx - m_ <= 8.f)){
      mn = fmaxf(m_, mx);
      float alpha = __expf(m_ - mn);
      l_ *= alpha;
      #pragma unroll
      for (int f = 0; f < 4; ++f) o_[f] *= alpha;
      m_ = mn;
    }
    float ps = 0.f;
    #pragma unroll
    for (int f = 0; f < 4; ++f){
      bf16x4 pk;
      #pragma unroll
      for (int rr = 0; rr < 4; ++rr){
        float p = __expf(s[f][rr] - mn);
        ps += p;
        pk[rr] = (short)f2b(p);
      }
      *(bf16x4*)&Plds[w][l15][f * 16 + l4 * 4] = pk;
    }
    ps += __shfl_xor(ps, 16);
    ps += __shfl_xor(ps, 32);
    l_ += ps;
    __builtin_amdgcn_s_setprio(1);
    #pragma unroll
    for (int ks = 0; ks < 2; ++ks){
      bf16x8 pf = *(const bf16x8*)&Plds[w][l15][ks * 32 + l4 * 8];
      #pragma unroll
      for (int f = 0; f < 4; ++f){
        bf16x8 vf = *(const bf16x8*)&Vlds[f * 16 + l15][ks * 32 + l4 * 8];
        o_[f] = __builtin_amdgcn_mfma_f32_16x16x32_bf16(vf, pf, o_[f], 0, 0, 0);
      }
    }
    __builtin_amdgcn_s_setprio(0);
  }
  int qt = qg * 4 + w;
  int u = ((bh << 7) + qt) * 4 + ch;
  size_t ob = (size_t)u * 1024;
  #pragma unroll
  for (int f = 0; f < 4; ++f){
    bf16x4 pk;
    #pragma unroll
    for (int rr = 0; rr < 4; ++rr) pk[rr] = (short)f2b(o_[f][rr]);
    *(bf16x4*)&po[ob + (size_t)l15 * 64 + f * 16 + l4 * 4] = pk;
  }
  if (l4 == 0){
    pml[(size_t)u * 32 + l15 * 2 + 0] = m_;
    pml[(size_t)u * 32 + l15 * 2 + 1] = l_;
  }
}

extern "C" void kernel_launch(void* const* d_in, const int* in_sizes, int n_in,
                              void* d_out, int out_size, void* d_ws, size_t ws_size,
                              hipStream_t stream){
  const float* seq    = (const float*)d_in[0];
  const float* ln1_g  = (const float*)d_in[1];
  const float* ln1_b  = (const float*)d_in[2];
  const float* wq     = (const float*)d_in[3];
  const float* bq     = (const float*)d_in[4];
  const float* wk     = (const float*)d_in[5];
  const float* bk     = (const float*)d_in[6];
  const float* wv     = (const float*)d_in[7];
  const float* bv     = (const float*)d_in[8];
  const float* wproj  = (const float*)d_in[9];
  const float* bproj  = (const float*)d_in[10];
  const float* ln2_g  = (const float*)d_in[11];
  const float* ln2_b  = (const float*)d_in[12];
  const float* w1     = (const float*)d_in[13];
  const float* b1     = (const float*)d_in[14];
  const float* w2     = (const float*)d_in[15];
  const float* b2     = (const float*)d_in[16];
  const float* lnf_g  = (const float*)d_in[17];
  const float* lnf_b  = (const float*)d_in[18];

  size_t off = 0;
  char* base = (char*)d_ws;
  auto carve = [&](size_t bytes) -> void* {
    void* p = base + off;
    off += (bytes + 255) & ~(size_t)255;
    return p;
  };
  float*  x      = (float*) carve((size_t)MPAD * DMOD * 4);
  ushort* qbuf   = (ushort*)carve((size_t)BSZ * NH * TPAD * HDIM * 2);
  ushort* kbuf   = (ushort*)carve((size_t)BSZ * NH * TPAD * HDIM * 2);
  ushort* vtbuf  = (ushort*)carve((size_t)BSZ * NH * TPAD * HDIM * 2);
  ushort* mid    = (ushort*)carve((size_t)MPAD * DFF * 2);
  ushort* wqkvT  = (ushort*)carve((size_t)NL * 768 * 256 * 2);
  ushort* wprojT = (ushort*)carve((size_t)NL * 256 * 256 * 2);
  ushort* w1T    = (ushort*)carve((size_t)NL * 1024 * 256 * 2);
  ushort* w2T    = (ushort*)carve((size_t)NL * 256 * 1024 * 2);
  float*  bqkv   = (float*) carve((size_t)NL * 768 * 4);
  ushort* po     = (ushort*)carve((size_t)4096 * 1024 * 2);
  float*  pml    = (float*) carve((size_t)4096 * 32 * 4);
  float*  pstatA = (float*) carve((size_t)MPAD * 8 * 4);
  float*  pstatB = (float*) carve((size_t)MPAD * 8 * 4);
  if (off > ws_size) return;

  // prep
  copy_in_k<<<dim3(MPAD/4), dim3(256), 0, stream>>>(seq, x, pstatA);
  wtrans_k<<<dim3(4, 4, NL),  dim3(256), 0, stream>>>(wq,    wqkvT,  256, 256,  768, 0);
  wtrans_k<<<dim3(4, 4, NL),  dim3(256), 0, stream>>>(wk,    wqkvT,  256, 256,  768, 256);
  wtrans_k<<<dim3(4, 4, NL),  dim3(256), 0, stream>>>(wv,    wqkvT,  256, 256,  768, 512);
  wtrans_k<<<dim3(4, 4, NL),  dim3(256), 0, stream>>>(wproj, wprojT, 256, 256,  256, 0);
  wtrans_k<<<dim3(4, 16, NL), dim3(256), 0, stream>>>(w1,    w1T,   1024, 256, 1024, 0);
  wtrans_k<<<dim3(16, 4, NL), dim3(256), 0, stream>>>(w2,    w2T,    256,1024,  256, 0);
  bqkv_k<<<dim3((NL*768 + 255)/256), dim3(256), 0, stream>>>(bq, bk, bv, bqkv);

  for (int l = 0; l < NL; ++l){
    gemm_k<768,256,1,0,0><<<dim3(64,12), dim3(256), 0, stream>>>(
        nullptr, x, pstatA, ln1_g + l*256, ln1_b + l*256, nullptr, nullptr,
        wqkvT + (size_t)l*768*256, bqkv + l*768, nullptr, nullptr, qbuf, kbuf, vtbuf);
    attn_tile_k<<<dim3(32,4,8), dim3(256), 0, stream>>>(qbuf, kbuf, vtbuf, po, pml);
    gemm_k<256,256,2,1,1><<<dim3(64,4), dim3(256), 0, stream>>>(
        nullptr, nullptr, nullptr, nullptr, nullptr, po, pml,
        wprojT + (size_t)l*256*256, bproj + l*256, x, pstatB, nullptr, nullptr, nullptr);
    gemm_k<1024,256,1,2,0><<<dim3(64,16), dim3(256), 0, stream>>>(
        nullptr, x, pstatB, ln2_g + l*256, ln2_b + l*256, nullptr, nullptr,
        w1T + (size_t)l*1024*256, b1 + l*1024, nullptr, nullptr, mid, nullptr, nullptr);
    gemm_k<256,1024,0,1,1><<<dim3(64,4), dim3(256), 0, stream>>>(
        mid, nullptr, nullptr, nullptr, nullptr, nullptr, nullptr,
        w2T + (size_t)l*256*1024, b2 + l*256, x, pstatA, nullptr, nullptr, nullptr);
  }
  lnf_k<<<dim3(BSZ*TSEQ/4), dim3(256), 0, stream>>>(x, lnf_g, lnf_b, (float*)d_out);
}

// Round 18
// 653.302 us; speedup vs baseline: 1.8108x; 1.0358x over previous
//
#include <hip/hip_runtime.h>
#include <math.h>

#define NL 10
#define BSZ 2
#define TSEQ 2040
#define TPAD 2048
#define DMOD 256
#define NH 4
#define HDIM 64
#define DFF 1024
#define MPAD (BSZ*TPAD)   // 4096
#define CKV 512           // KV chunk per attention block

typedef __attribute__((ext_vector_type(8))) short bf16x8;
typedef __attribute__((ext_vector_type(4))) short bf16x4;
typedef __attribute__((ext_vector_type(4))) float f32x4;

__device__ __forceinline__ ushort f2b(float f){
  union { float f; unsigned u; } v; v.f = f;
  unsigned u = v.u;
  return (ushort)((u + 0x7FFFu + ((u >> 16) & 1u)) >> 16);
}
__device__ __forceinline__ float b2f(ushort h){
  union { unsigned u; float f; } v; v.u = ((unsigned)h) << 16; return v.f;
}

// ---- copy sequences -> padded x [B][2048][256] f32 (zero pad rows) + row stats ----
__global__ __launch_bounds__(256) void copy_in_k(const float* __restrict__ seq, float* __restrict__ x,
                                                 float* __restrict__ pstat){
  int idx = blockIdx.x * 256 + threadIdx.x;
  int row = idx >> 6, c = idx & 63;
  int b = row >> 11, t = row & 2047;
  float4 v = {0.f, 0.f, 0.f, 0.f};
  if (t < TSEQ) v = ((const float4*)(seq + ((size_t)(b * TSEQ + t)) * DMOD))[c];
  ((float4*)(x + (size_t)row * DMOD))[c] = v;
  float s  = v.x + v.y + v.z + v.w;
  float s2 = v.x*v.x + v.y*v.y + v.z*v.z + v.w*v.w;
  #pragma unroll
  for (int off = 1; off < 16; off <<= 1){ s += __shfl_xor(s, off); s2 += __shfl_xor(s2, off); }
  if ((c & 15) == 0){
    float2 pr; pr.x = s; pr.y = s2;
    ((float2*)pstat)[(size_t)row * 4 + (c >> 4)] = pr;
  }
}

// ---- LDS-tiled transpose+cast: src (L,K,N) f32 -> dst [l][row0+n][k] bf16 ----
__global__ __launch_bounds__(256) void wtrans_k(const float* __restrict__ src, ushort* __restrict__ dst,
                                                int N, int K, int NTOT, int row0){
  __shared__ ushort tile[64][72];
  int tid = threadIdx.x;
  int kk0 = blockIdx.x * 64, n0 = blockIdx.y * 64, l = blockIdx.z;
  int kl = tid >> 2, nq = tid & 3;
  const float* sp = src + ((size_t)(l * K + kk0 + kl)) * N + n0 + nq * 16;
  #pragma unroll
  for (int i = 0; i < 4; ++i){
    float4 v = ((const float4*)sp)[i];
    int nb = nq * 16 + i * 4;
    tile[nb + 0][kl] = f2b(v.x);
    tile[nb + 1][kl] = f2b(v.y);
    tile[nb + 2][kl] = f2b(v.z);
    tile[nb + 3][kl] = f2b(v.w);
  }
  __syncthreads();
  int r = tid >> 2, cq = (tid & 3) * 16;
  ushort* dp = dst + ((size_t)(l * NTOT + row0 + n0 + r)) * K + kk0 + cq;
  *(bf16x8*)dp       = *(const bf16x8*)&tile[r][cq];
  *(bf16x8*)(dp + 8) = *(const bf16x8*)&tile[r][cq + 8];
}

// ---- concat qkv biases ----
__global__ __launch_bounds__(256) void bqkv_k(const float* __restrict__ bq, const float* __restrict__ bk,
                                              const float* __restrict__ bv, float* __restrict__ bqkv){
  int idx = blockIdx.x * 256 + threadIdx.x;
  if (idx >= NL * 768) return;
  int l = idx / 768, n = idx % 768;
  float v = (n < 256) ? bq[l * 256 + n] : ((n < 512) ? bk[l * 256 + n - 256] : bv[l * 256 + n - 512]);
  bqkv[idx] = v;
}

// ---- final layernorm -> f32 d_out (compact rows); 4 rows per block ----
__global__ __launch_bounds__(256) void lnf_k(const float* __restrict__ x, const float* __restrict__ g,
                                             const float* __restrict__ be, float* __restrict__ outf){
  int tid = threadIdx.x;
  int row = blockIdx.x * 4 + (tid >> 6), lane = tid & 63;
  int b = row / TSEQ, t = row % TSEQ;
  int irow = b * TPAD + t;
  float4 xv = ((const float4*)(x + (size_t)irow * DMOD))[lane];
  float s  = xv.x + xv.y + xv.z + xv.w;
  float s2 = xv.x*xv.x + xv.y*xv.y + xv.z*xv.z + xv.w*xv.w;
  #pragma unroll
  for (int off = 1; off < 64; off <<= 1){ s += __shfl_xor(s, off); s2 += __shfl_xor(s2, off); }
  float mu = s * (1.f/256.f);
  float var = s2 * (1.f/256.f) - mu * mu;
  float rs = rsqrtf(var + 1e-5f);
  float4 gv = ((const float4*)g)[lane];
  float4 bv = ((const float4*)be)[lane];
  float4 ov;
  ov.x = (xv.x - mu) * rs * gv.x + bv.x;
  ov.y = (xv.y - mu) * rs * gv.y + bv.y;
  ov.z = (xv.z - mu) * rs * gv.z + bv.z;
  ov.w = (xv.w - mu) * rs * gv.w + bv.w;
  ((float4*)(outf + (size_t)row * DMOD))[lane] = ov;
}

// ---- BMx64-tile GEMM, BK=128 ----
// BM=64: 4 waves as 2x2 (32-row x 32-col each). BM=32: 4 waves as 1x4 (32-row x 16-col each).
// AMODE 0: A = Ab; AMODE 1 (BM=64 only): A = LN(Af) via pstat_in; AMODE 2: A = merged attn
// EPI 0: QKV scatter (q pre-scaled; v [b,h,hd,t]); EPI 1: xres += v; EPI 2: GELU -> o0
// STATS 1: per-(row, colblock64) partial {sum,sumsq} of x_new -> pstat_out
template<int N, int K, int AMODE, int EPI, int STATS, int BM>
__global__ __launch_bounds__(256) void gemm_k(
    const ushort* __restrict__ Ab, const float* __restrict__ Af,
    const float* __restrict__ pstat_in, const float* __restrict__ lng, const float* __restrict__ lnb,
    const ushort* __restrict__ po, const float* __restrict__ pml,
    const ushort* __restrict__ Bt, const float* __restrict__ bias,
    float* __restrict__ xres, float* __restrict__ pstat_out,
    ushort* __restrict__ o0, ushort* __restrict__ o1, ushort* __restrict__ o2){
  constexpr int NC = (BM == 64) ? 2 : 1;      // col fragments per wave
  constexpr int NW = (BM == 64) ? 2 : 4;      // col groups (waves in col dim)
  __shared__ ushort Alds[2][BM][72];
  __shared__ ushort Blds[2][64][72];
  __shared__ float statLds[STATS ? BM : 1][NW][2];
  int tid = threadIdx.x;
  int w = tid >> 6, lane = tid & 63;
  int wr = (BM == 64) ? (w >> 1) : 0;
  int wc = (BM == 64) ? (w & 1) : w;
  int l15 = lane & 15, l4 = lane >> 4;
  int row0 = blockIdx.x * BM, col0 = blockIdx.y * 64;
  int r = tid >> 3, c8 = (tid & 7) * 8;       // r in [0,32)

  float muA = 0.f, rsA = 0.f, muB = 0.f, rsB = 0.f;
  if (AMODE == 1){
    const float4* pa = (const float4*)(pstat_in + (size_t)(row0 + r) * 8);
    float4 a0 = pa[0], a1 = pa[1];
    float s = a0.x + a0.z + a1.x + a1.z, q = a0.y + a0.w + a1.y + a1.w;
    muA = s * (1.f/256.f);
    rsA = rsqrtf(q * (1.f/256.f) - muA * muA + 1e-5f);
    const float4* pb = (const float4*)(pstat_in + (size_t)(row0 + r + 32) * 8);
    float4 b0 = pb[0], b1 = pb[1];
    s = b0.x + b0.z + b1.x + b1.z; q = b0.y + b0.w + b1.y + b1.w;
    muB = s * (1.f/256.f);
    rsB = rsqrtf(q * (1.f/256.f) - muB * muB + 1e-5f);
  }

  f32x4 zero = {0.f, 0.f, 0.f, 0.f};
  f32x4 acc[2][NC];
  #pragma unroll
  for (int mr = 0; mr < 2; ++mr)
    #pragma unroll
    for (int nc = 0; nc < NC; ++nc) acc[mr][nc] = zero;

  for (int k0 = 0; k0 < K; k0 += 128){
    #pragma unroll
    for (int ck = 0; ck < 2; ++ck){
      int kk = k0 + ck * 64;
      // ---- stage A (BM rows) ----
      #pragma unroll
      for (int it = 0; it < BM / 32; ++it){
        int rr = r + it * 32;
        if (AMODE == 0){
          *(bf16x8*)&Alds[ck][rr][c8] = *(const bf16x8*)(Ab + (size_t)(row0 + rr) * K + kk + c8);
        } else if (AMODE == 1){
          float mu = it ? muB : muA, rs = it ? rsB : rsA;
          const float4* xp = (const float4*)(Af + (size_t)(row0 + rr) * 256 + kk + c8);
          float4 xa = xp[0], xb = xp[1];
          const float4* gp = (const float4*)(lng + kk + c8);
          const float4* bp = (const float4*)(lnb + kk + c8);
          float4 ga = gp[0], gb = gp[1], ba = bp[0], bb = bp[1];
          bf16x8 pk;
          pk[0] = (short)f2b((xa.x - mu) * rs * ga.x + ba.x);
          pk[1] = (short)f2b((xa.y - mu) * rs * ga.y + ba.y);
          pk[2] = (short)f2b((xa.z - mu) * rs * ga.z + ba.z);
          pk[3] = (short)f2b((xa.w - mu) * rs * ga.w + ba.w);
          pk[4] = (short)f2b((xb.x - mu) * rs * gb.x + bb.x);
          pk[5] = (short)f2b((xb.y - mu) * rs * gb.y + bb.y);
          pk[6] = (short)f2b((xb.z - mu) * rs * gb.z + bb.z);
          pk[7] = (short)f2b((xb.w - mu) * rs * gb.w + bb.w);
          *(bf16x8*)&Alds[ck][rr][c8] = pk;
        } else {
          int m = row0 + rr;
          int t = m & 2047, b_ = m >> 11;
          int qt = t >> 4, r16 = t & 15;
          int hh = kk >> 6;
          int u0 = (((b_ * NH + hh) << 7) + qt) << 2;
          int je = ((qt * 16 + 15) / 17) * 17 + 17; je = je < TSEQ ? je : TSEQ;
          int nch = (je + CKV - 1) >> 9;
          float mm[4]; float mg = -1e30f;
          #pragma unroll
          for (int ch = 0; ch < 4; ++ch){
            mm[ch] = (ch < nch) ? pml[(size_t)(u0 + ch) * 32 + r16 * 2] : -1e30f;
            mg = fmaxf(mg, mm[ch]);
          }
          float aw[4]; float lg = 0.f;
          #pragma unroll
          for (int ch = 0; ch < 4; ++ch){
            float ll = (ch < nch) ? pml[(size_t)(u0 + ch) * 32 + r16 * 2 + 1] : 0.f;
            aw[ch] = (ch < nch) ? __expf(mm[ch] - mg) : 0.f;
            lg += aw[ch] * ll;
          }
          float inv = 1.f / lg;
          float av[8] = {0.f,0.f,0.f,0.f,0.f,0.f,0.f,0.f};
          #pragma unroll
          for (int ch = 0; ch < 4; ++ch){
            bf16x8 pv = *(const bf16x8*)(po + (size_t)(u0 + ch) * 1024 + r16 * 64 + c8);
            #pragma unroll
            for (int j = 0; j < 8; ++j) av[j] += aw[ch] * b2f((ushort)pv[j]);
          }
          bf16x8 pk;
          #pragma unroll
          for (int j = 0; j < 8; ++j) pk[j] = (short)f2b(av[j] * inv);
          *(bf16x8*)&Alds[ck][rr][c8] = pk;
        }
      }
      // ---- stage B (64 rows) ----
      #pragma unroll
      for (int it = 0; it < 2; ++it){
        int rr = r + it * 32;
        *(bf16x8*)&Blds[ck][rr][c8] = *(const bf16x8*)(Bt + (size_t)(col0 + rr) * K + kk + c8);
      }
    }
    __syncthreads();
    #pragma unroll
    for (int ck = 0; ck < 2; ++ck){
      #pragma unroll
      for (int ks = 0; ks < 2; ++ks){
        bf16x8 af[2], bfr[NC];
        #pragma unroll
        for (int i = 0; i < 2; ++i)
          af[i] = *(const bf16x8*)&Alds[ck][wr * 32 + i * 16 + l15][ks * 32 + l4 * 8];
        #pragma unroll
        for (int i = 0; i < NC; ++i)
          bfr[i] = *(const bf16x8*)&Blds[ck][wc * (16 * NC) + i * 16 + l15][ks * 32 + l4 * 8];
        #pragma unroll
        for (int mr = 0; mr < 2; ++mr)
          #pragma unroll
          for (int nc = 0; nc < NC; ++nc)
            acc[mr][nc] = __builtin_amdgcn_mfma_f32_16x16x32_bf16(af[mr], bfr[nc], acc[mr][nc], 0, 0, 0);
      }
    }
    __syncthreads();
  }

  float sr_[2][4], q2_[2][4];
  if (STATS){
    #pragma unroll
    for (int mr = 0; mr < 2; ++mr)
      #pragma unroll
      for (int rr = 0; rr < 4; ++rr){ sr_[mr][rr] = 0.f; q2_[mr][rr] = 0.f; }
  }
  #pragma unroll
  for (int mr = 0; mr < 2; ++mr){
    #pragma unroll
    for (int nc = 0; nc < NC; ++nc){
      #pragma unroll
      for (int rr = 0; rr < 4; ++rr){
        int m = row0 + wr * 32 + mr * 16 + l4 * 4 + rr;
        int n = col0 + wc * (16 * NC) + nc * 16 + l15;
        float v = acc[mr][nc][rr] + bias[n];
        if (EPI == 0){
          int b = m >> 11, t = m & 2047;
          int which = n >> 8, hn = n & 255, hh = hn >> 6, hd = hn & 63;
          if (which == 0)      o0[(((size_t)(b * NH + hh)) * TPAD + t) * HDIM + hd] = f2b(v * 0.125f);
          else if (which == 1) o1[(((size_t)(b * NH + hh)) * TPAD + t) * HDIM + hd] = f2b(v);
          else                 o2[(((size_t)(b * NH + hh)) * HDIM + hd) * TPAD + t] = f2b(v);
        } else if (EPI == 1){
          float xn = xres[(size_t)m * 256 + n] + v;
          xres[(size_t)m * 256 + n] = xn;
          if (STATS){ sr_[mr][rr] += xn; q2_[mr][rr] += xn * xn; }
        } else {
          float uu = 0.7978845608028654f * (v + 0.044715f * v * v * v);
          float e = __expf(2.f * uu);
          float th = 1.f - 2.f / (e + 1.f);
          o0[(size_t)m * N + n] = f2b(0.5f * v * (1.f + th));
        }
      }
    }
  }
  if (STATS){
    #pragma unroll
    for (int mr = 0; mr < 2; ++mr){
      #pragma unroll
      for (int rr = 0; rr < 4; ++rr){
        float s = sr_[mr][rr], q = q2_[mr][rr];
        #pragma unroll
        for (int off = 1; off < 16; off <<= 1){ s += __shfl_xor(s, off); q += __shfl_xor(q, off); }
        if (l15 == 0){
          int rl = wr * 32 + mr * 16 + l4 * 4 + rr;
          statLds[rl][wc][0] = s;
          statLds[rl][wc][1] = q;
        }
      }
    }
    __syncthreads();
    if (tid < BM){
      float ssum = 0.f, qsum = 0.f;
      #pragma unroll
      for (int g = 0; g < NW; ++g){ ssum += statLds[tid][g][0]; qsum += statLds[tid][g][1]; }
      float2 pr; pr.x = ssum; pr.y = qsum;
      ((float2*)pstat_out)[(size_t)(row0 + tid) * 4 + blockIdx.y] = pr;
    }
  }
}

// ---- split-KV flash attention: swapped-operand QK^T, per-lane softmax,
//      defer-max rescale (T13) + setprio around MFMA clusters (T5) ----
// block = (qg 64 q-rows, ch 512-KV chunk, bh); grid (32,4,8); 4 waves x 16 q each.
__global__ __launch_bounds__(256) void attn_tile_k(const ushort* __restrict__ qq, const ushort* __restrict__ kkk,
                                                   const ushort* __restrict__ vt,
                                                   ushort* __restrict__ po, float* __restrict__ pml){
  __shared__ ushort Klds[64][72];
  __shared__ ushort Vlds[64][72];
  __shared__ ushort Plds[4][16][72];
  int tid = threadIdx.x, w = tid >> 6, lane = tid & 63;
  int l15 = lane & 15, l4 = lane >> 4;
  int qg = blockIdx.x, ch = blockIdx.y, bh = blockIdx.z;
  int r0 = qg * 64;
  int je_blk = ((r0 + 63) / 17 + 1) * 17; je_blk = je_blk < TSEQ ? je_blk : TSEQ;
  int jstart = ch * CKV;
  if (jstart >= je_blk) return;                       // idle block (uniform)
  int jend = (jstart + CKV) < je_blk ? (jstart + CKV) : je_blk;

  int i0 = r0 + w * 16;
  int je_w = ((i0 + 15) / 17 + 1) * 17; je_w = je_w < TSEQ ? je_w : TSEQ;

  const ushort* qb = qq  + (size_t)bh * TPAD * HDIM;
  const ushort* kb = kkk + (size_t)bh * TPAD * HDIM;
  const ushort* vb = vt  + (size_t)bh * HDIM * TPAD;

  int ig = i0 + l15;                                  // this lane's query row
  int ibase = (int)((unsigned)ig / 17u) * 17;         // its block start
  bf16x8 aq0 = *(const bf16x8*)(qb + (size_t)ig * HDIM + l4 * 8);
  bf16x8 aq1 = *(const bf16x8*)(qb + (size_t)ig * HDIM + 32 + l4 * 8);

  f32x4 zero = {0.f, 0.f, 0.f, 0.f};
  float m_ = -1e30f, l_ = 0.f;
  f32x4 o_[4];
  o_[0] = zero; o_[1] = zero; o_[2] = zero; o_[3] = zero;

  int sr = tid >> 2, sc = (tid & 3) * 16;             // staging: 4 threads/row, 32B each
  for (int j0 = jstart; j0 < jend; j0 += 64){
    __syncthreads();
    *(bf16x8*)&Klds[sr][sc]     = *(const bf16x8*)(kb + (size_t)(j0 + sr) * HDIM + sc);
    *(bf16x8*)&Klds[sr][sc + 8] = *(const bf16x8*)(kb + (size_t)(j0 + sr) * HDIM + sc + 8);
    *(bf16x8*)&Vlds[sr][sc]     = *(const bf16x8*)(vb + (size_t)sr * TPAD + j0 + sc);
    *(bf16x8*)&Vlds[sr][sc + 8] = *(const bf16x8*)(vb + (size_t)sr * TPAD + j0 + sc + 8);
    __syncthreads();
    if (j0 >= je_w) continue;
    f32x4 s[4];
    __builtin_amdgcn_s_setprio(1);
    #pragma unroll
    for (int f = 0; f < 4; ++f){
      bf16x8 kf = *(const bf16x8*)&Klds[f * 16 + l15][l4 * 8];
      s[f] = __builtin_amdgcn_mfma_f32_16x16x32_bf16(kf, aq0, zero, 0, 0, 0);
    }
    #pragma unroll
    for (int f = 0; f < 4; ++f){
      bf16x8 kf = *(const bf16x8*)&Klds[f * 16 + l15][32 + l4 * 8];
      s[f] = __builtin_amdgcn_mfma_f32_16x16x32_bf16(kf, aq1, s[f], 0, 0, 0);
    }
    __builtin_amdgcn_s_setprio(0);
    if (j0 + 63 > i0){
      #pragma unroll
      for (int f = 0; f < 4; ++f){
        #pragma unroll
        for (int rr = 0; rr < 4; ++rr){
          int jg = j0 + f * 16 + l4 * 4 + rr;
          bool ok = (jg <= ig) || ((unsigned)(jg - ibase) < 17u);
          s[f][rr] = ok ? s[f][rr] : -1e30f;
        }
      }
    }
    float mf0 = fmaxf(fmaxf(s[0][0], s[0][1]), fmaxf(s[0][2], s[0][3]));
    float mf1 = fmaxf(fmaxf(s[1][0], s[1][1]), fmaxf(s[1][2], s[1][3]));
    float mf2 = fmaxf(fmaxf(s[2][0], s[2][1]), fmaxf(s[2][2], s[2][3]));
    float mf3 = fmaxf(fmaxf(s[3][0], s[3][1]), fmaxf(s[3][2], s[3][3]));
    float mx = fmaxf(fmaxf(mf0, mf1), fmaxf(mf2, mf3));
    mx = fmaxf(mx, __shfl_xor(mx, 16));
    mx = fmaxf(mx, __shfl_xor(mx, 32));
    // defer-max: skip O/l rescale when max growth is bounded (P <= e^8, bf16-safe)
    float mn = m_;
    if (!__all(mx - m_ <= 8.f)){
      mn = fmaxf(m_, mx);
      float alpha = __expf(m_ - mn);
      l_ *= alpha;
      #pragma unroll
      for (int f = 0; f < 4; ++f) o_[f] *= alpha;
      m_ = mn;
    }
    float ps = 0.f;
    #pragma unroll
    for (int f = 0; f < 4; ++f){
      bf16x4 pk;
      #pragma unroll
      for (int rr = 0; rr < 4; ++rr){
        float p = __expf(s[f][rr] - mn);
        ps += p;
        pk[rr] = (short)f2b(p);
      }
      *(bf16x4*)&Plds[w][l15][f * 16 + l4 * 4] = pk;
    }
    ps += __shfl_xor(ps, 16);
    ps += __shfl_xor(ps, 32);
    l_ += ps;
    __builtin_amdgcn_s_setprio(1);
    #pragma unroll
    for (int ks = 0; ks < 2; ++ks){
      bf16x8 pf = *(const bf16x8*)&Plds[w][l15][ks * 32 + l4 * 8];
      #pragma unroll
      for (int f = 0; f < 4; ++f){
        bf16x8 vf = *(const bf16x8*)&Vlds[f * 16 + l15][ks * 32 + l4 * 8];
        o_[f] = __builtin_amdgcn_mfma_f32_16x16x32_bf16(vf, pf, o_[f], 0, 0, 0);
      }
    }
    __builtin_amdgcn_s_setprio(0);
  }
  int qt = qg * 4 + w;
  int u = ((bh << 7) + qt) * 4 + ch;
  size_t ob = (size_t)u * 1024;
  #pragma unroll
  for (int f = 0; f < 4; ++f){
    bf16x4 pk;
    #pragma unroll
    for (int rr = 0; rr < 4; ++rr) pk[rr] = (short)f2b(o_[f][rr]);
    *(bf16x4*)&po[ob + (size_t)l15 * 64 + f * 16 + l4 * 4] = pk;
  }
  if (l4 == 0){
    pml[(size_t)u * 32 + l15 * 2 + 0] = m_;
    pml[(size_t)u * 32 + l15 * 2 + 1] = l_;
  }
}

extern "C" void kernel_launch(void* const* d_in, const int* in_sizes, int n_in,
                              void* d_out, int out_size, void* d_ws, size_t ws_size,
                              hipStream_t stream){
  const float* seq    = (const float*)d_in[0];
  const float* ln1_g  = (const float*)d_in[1];
  const float* ln1_b  = (const float*)d_in[2];
  const float* wq     = (const float*)d_in[3];
  const float* bq     = (const float*)d_in[4];
  const float* wk     = (const float*)d_in[5];
  const float* bk     = (const float*)d_in[6];
  const float* wv     = (const float*)d_in[7];
  const float* bv     = (const float*)d_in[8];
  const float* wproj  = (const float*)d_in[9];
  const float* bproj  = (const float*)d_in[10];
  const float* ln2_g  = (const float*)d_in[11];
  const float* ln2_b  = (const float*)d_in[12];
  const float* w1     = (const float*)d_in[13];
  const float* b1     = (const float*)d_in[14];
  const float* w2     = (const float*)d_in[15];
  const float* b2     = (const float*)d_in[16];
  const float* lnf_g  = (const float*)d_in[17];
  const float* lnf_b  = (const float*)d_in[18];

  size_t off = 0;
  char* base = (char*)d_ws;
  auto carve = [&](size_t bytes) -> void* {
    void* p = base + off;
    off += (bytes + 255) & ~(size_t)255;
    return p;
  };
  float*  x      = (float*) carve((size_t)MPAD * DMOD * 4);
  ushort* qbuf   = (ushort*)carve((size_t)BSZ * NH * TPAD * HDIM * 2);
  ushort* kbuf   = (ushort*)carve((size_t)BSZ * NH * TPAD * HDIM * 2);
  ushort* vtbuf  = (ushort*)carve((size_t)BSZ * NH * TPAD * HDIM * 2);
  ushort* mid    = (ushort*)carve((size_t)MPAD * DFF * 2);
  ushort* wqkvT  = (ushort*)carve((size_t)NL * 768 * 256 * 2);
  ushort* wprojT = (ushort*)carve((size_t)NL * 256 * 256 * 2);
  ushort* w1T    = (ushort*)carve((size_t)NL * 1024 * 256 * 2);
  ushort* w2T    = (ushort*)carve((size_t)NL * 256 * 1024 * 2);
  float*  bqkv   = (float*) carve((size_t)NL * 768 * 4);
  ushort* po     = (ushort*)carve((size_t)4096 * 1024 * 2);
  float*  pml    = (float*) carve((size_t)4096 * 32 * 4);
  float*  pstatA = (float*) carve((size_t)MPAD * 8 * 4);
  float*  pstatB = (float*) carve((size_t)MPAD * 8 * 4);
  if (off > ws_size) return;

  // prep
  copy_in_k<<<dim3(MPAD/4), dim3(256), 0, stream>>>(seq, x, pstatA);
  wtrans_k<<<dim3(4, 4, NL),  dim3(256), 0, stream>>>(wq,    wqkvT,  256, 256,  768, 0);
  wtrans_k<<<dim3(4, 4, NL),  dim3(256), 0, stream>>>(wk,    wqkvT,  256, 256,  768, 256);
  wtrans_k<<<dim3(4, 4, NL),  dim3(256), 0, stream>>>(wv,    wqkvT,  256, 256,  768, 512);
  wtrans_k<<<dim3(4, 4, NL),  dim3(256), 0, stream>>>(wproj, wprojT, 256, 256,  256, 0);
  wtrans_k<<<dim3(4, 16, NL), dim3(256), 0, stream>>>(w1,    w1T,   1024, 256, 1024, 0);
  wtrans_k<<<dim3(16, 4, NL), dim3(256), 0, stream>>>(w2,    w2T,    256,1024,  256, 0);
  bqkv_k<<<dim3((NL*768 + 255)/256), dim3(256), 0, stream>>>(bq, bk, bv, bqkv);

  for (int l = 0; l < NL; ++l){
    gemm_k<768,256,1,0,0,64><<<dim3(64,12), dim3(256), 0, stream>>>(
        nullptr, x, pstatA, ln1_g + l*256, ln1_b + l*256, nullptr, nullptr,
        wqkvT + (size_t)l*768*256, bqkv + l*768, nullptr, nullptr, qbuf, kbuf, vtbuf);
    attn_tile_k<<<dim3(32,4,8), dim3(256), 0, stream>>>(qbuf, kbuf, vtbuf, po, pml);
    gemm_k<256,256,2,1,1,32><<<dim3(128,4), dim3(256), 0, stream>>>(
        nullptr, nullptr, nullptr, nullptr, nullptr, po, pml,
        wprojT + (size_t)l*256*256, bproj + l*256, x, pstatB, nullptr, nullptr, nullptr);
    gemm_k<1024,256,1,2,0,64><<<dim3(64,16), dim3(256), 0, stream>>>(
        nullptr, x, pstatB, ln2_g + l*256, ln2_b + l*256, nullptr, nullptr,
        w1T + (size_t)l*1024*256, b1 + l*1024, nullptr, nullptr, mid, nullptr, nullptr);
    gemm_k<256,1024,0,1,1,32><<<dim3(128,4), dim3(256), 0, stream>>>(
        mid, nullptr, nullptr, nullptr, nullptr, nullptr, nullptr,
        w2T + (size_t)l*256*1024, b2 + l*256, x, pstatA, nullptr, nullptr, nullptr);
  }
  lnf_k<<<dim3(BSZ*TSEQ/4), dim3(256), 0, stream>>>(x, lnf_g, lnf_b, (float*)d_out);
}